// Round 3
// baseline (783.611 us; speedup 1.0000x reference)
//
#include <hip/hip_runtime.h>
#include <hip/hip_bf16.h>

typedef __hip_bfloat16 bf16;
#define DEVI __device__ __forceinline__

typedef __bf16 bf16x8 __attribute__((ext_vector_type(8)));
typedef __bf16 bf16x4 __attribute__((ext_vector_type(4)));
typedef float  f32x4  __attribute__((ext_vector_type(4)));

DEVI float bf2f(bf16 v) { return __bfloat162float(v); }
DEVI bf16 f2bf(float v) { return __float2bfloat16(v); }

DEVI unsigned short bfbits(float x) {
    bf16 h = __float2bfloat16(x);
    return *reinterpret_cast<unsigned short*>(&h);
}
DEVI unsigned int pack2(float x, float y) {
    return (unsigned int)bfbits(x) | ((unsigned int)bfbits(y) << 16);
}
DEVI bf16x8 pack8(float4 lo, float4 hi) {
    union { unsigned int u[4]; bf16x8 v; } z;
    z.u[0] = pack2(lo.x, lo.y); z.u[1] = pack2(lo.z, lo.w);
    z.u[2] = pack2(hi.x, hi.y); z.u[3] = pack2(hi.z, hi.w);
    return z.v;
}
// LDS bf16x8 load from an 8-byte-aligned (not 16) address: two b64 halves
DEVI bf16x8 ld8h(const bf16* p) {
    bf16x4 lo = *(const bf16x4*)p;
    bf16x4 hi = *(const bf16x4*)(p + 4);
    return __builtin_shufflevector(lo, hi, 0, 1, 2, 3, 4, 5, 6, 7);
}

// ---------------------------------------------------------------------------
// Prep A: reorder qkv weights per head into [h][96][192] bf16, fold 1/sqrt(32)
// into the q rows and q bias. qkv_bb fp32 [576] in [h][96] order.
// ---------------------------------------------------------------------------
__global__ __launch_bounds__(256) void prep_attn_w(
    const float* __restrict__ qkv_w, const float* __restrict__ qkv_b,
    bf16* __restrict__ qkv_wb, float* __restrict__ qkv_bb)
{
    const float scale = 0.17677669529663687f;
    int idx = blockIdx.x * 256 + threadIdx.x;
    if (idx < 110592) {
        int c = idx % 192, d = idx / 192;
        int h = d / 96, q2 = d - h * 96, seg = q2 >> 5, rr = q2 & 31;
        float v = qkv_w[(size_t)(seg * 192 + h * 32 + rr) * 192 + c];
        if (seg == 0) v *= scale;
        qkv_wb[idx] = f2bf(v);
    }
    if (idx < 576) {
        int h = idx / 96, q2 = idx - h * 96, seg = q2 >> 5, rr = q2 & 31;
        float b = qkv_b[seg * 192 + h * 32 + rr];
        if (seg == 0) b *= scale;
        qkv_bb[idx] = b;
    }
}

// ---------------------------------------------------------------------------
// Prep B: earth bias tiles, TRANSPOSED layout biasT[wb][h][key][tok] bf16
// (so the attn kernel's gather bt[key*144+tok] is lane-contiguous in tok).
// ---------------------------------------------------------------------------
__global__ __launch_bounds__(256) void prep_bias(
    const float* __restrict__ bias_table, bf16* __restrict__ biasT)
{
    int idx = blockIdx.x * 256 + threadIdx.x;
    if (idx >= 7962624) return;
    int t = idx % 144;             // tok (query)
    int k = (idx / 144) % 144;     // key
    int r2 = idx / 20736;
    int h = r2 % 6, wb = r2 / 6;
    int tzq = t / 72, thq = (t / 12) % 6, twq = t % 12;
    int tzk = k / 72, thk = (k / 12) % 6, twk = k % 12;
    int bidx = (tzq + 2 * tzk) * 828 + (thq + 6 * thk) * 23 + (twq - twk + 11);
    biasT[idx] = f2bf(bias_table[(size_t)(bidx * 64 + wb) * 6 + h]);
}

// ---------------------------------------------------------------------------
// Kernel 1 (MFMA): windowed attention, one block per (window, head), 4 waves.
// Swapped QK^T (S^T = K·Q^T) so each lane owns whole query rows ->
// in-register softmax (2 shfl_xor) and in-register P->A-frag build for PV
// (cross-quad shfl exchange). NO LDS for P, ONE barrier per block.
// LDS 30976 B. Waves split over the 9 query tiles {w, w+4, w+8}.
// ---------------------------------------------------------------------------
__global__ __launch_bounds__(256, 3) void attn_mfma_kernel(
    const float* __restrict__ x, const bf16* __restrict__ qkv_wb,
    const float* __restrict__ qkv_bb, const bf16* __restrict__ biasT,
    bf16* __restrict__ attn_out)
{
    // LDS: Qs [144][36] @0 (10368) | Ks [144][36] @10368 | VTs [32][160] @20736
    __shared__ alignas(16) char sm[30976];
    bf16* Qs  = (bf16*)sm;
    bf16* Ks  = (bf16*)(sm + 10368);
    bf16* VTs = (bf16*)(sm + 20736);

    const int tid  = threadIdx.x;
    const int wave = tid >> 6;
    const int lane = tid & 63;
    const int quad = lane >> 4;
    const int l15  = lane & 15;

    // XCD-chunked swizzle: 5760 blocks = 8 XCDs x 720; head-fastest order so
    // the 6 blocks of one window (sharing x) and nearby bias tiles stay in
    // one XCD's L2.
    const int bid     = blockIdx.x;
    const int logical = (bid & 7) * 720 + (bid >> 3);
    const int wi      = logical / 6;
    const int head    = logical % 6;
    const int ww_  = wi % 15;
    const int hw   = (wi / 15) % 16;
    const int zw   = wi / 240;
    const int wb   = zw * 16 + hw;

    // zero VT pad cols [144,160) (read by PV ks=4 with zero A-frag; must not be NaN)
    for (int i = tid; i < 512; i += 256) {
        int d = i >> 4, c = i & 15;
        VTs[d * 160 + 144 + c] = f2bf(0.f);
    }

    // ---- load A-fragments of x window (fp32 -> bf16) ----
    bf16x8 af[3][6];
#pragma unroll
    for (int i = 0; i < 3; ++i) {
        int mt = wave + 4 * i;
        if (mt < 9) {
            int t  = mt * 16 + l15;
            int tz = t / 72, rr = t - tz * 72;
            int th = rr / 12, tw = rr - th * 12;
            int lat = hw * 6 + th - 2;
            bool valid = (lat >= 0 && lat < 91);
            size_t base = ((size_t)((zw * 2 + tz) * 91 + (valid ? lat : 0)) * 180
                           + ww_ * 12 + tw) * 192;
#pragma unroll
            for (int ks = 0; ks < 6; ++ks) {
                float4 lo = make_float4(0.f, 0.f, 0.f, 0.f);
                float4 hi = make_float4(0.f, 0.f, 0.f, 0.f);
                if (valid) {
                    lo = *(const float4*)(x + base + ks * 32 + quad * 8);
                    hi = *(const float4*)(x + base + ks * 32 + quad * 8 + 4);
                }
                af[i][ks] = pack8(lo, hi);
            }
        }
    }

    // ---- QKV GEMM: 6 N-tiles (q0 q1 k0 k1 v0 v1) ----
    for (int nt = 0; nt < 6; ++nt) {
        const bf16* wrow = qkv_wb + (size_t)(head * 96 + nt * 16 + l15) * 192;
        bf16x8 bw[6];
#pragma unroll
        for (int ks = 0; ks < 6; ++ks)
            bw[ks] = *(const bf16x8*)(wrow + ks * 32 + quad * 8);
        float bias = qkv_bb[head * 96 + nt * 16 + l15];

        f32x4 acc[3];
#pragma unroll
        for (int i = 0; i < 3; ++i) acc[i] = (f32x4){0.f, 0.f, 0.f, 0.f};
#pragma unroll
        for (int ks = 0; ks < 6; ++ks)
#pragma unroll
            for (int i = 0; i < 3; ++i) {
                int mt = wave + 4 * i;
                if (mt < 9)
                    acc[i] = __builtin_amdgcn_mfma_f32_16x16x32_bf16(
                        af[i][ks], bw[ks], acc[i], 0, 0, 0);
            }
#pragma unroll
        for (int i = 0; i < 3; ++i) {
            int mt = wave + 4 * i;
            if (mt < 9) {
#pragma unroll
                for (int r = 0; r < 4; ++r) {
                    float v = acc[i][r] + bias;
                    int tok = mt * 16 + quad * 4 + r;
                    if (nt < 2)      Qs[tok * 36 + nt * 16 + l15] = f2bf(v);
                    else if (nt < 4) Ks[tok * 36 + (nt - 2) * 16 + l15] = f2bf(v);
                    else             VTs[((nt - 4) * 16 + l15) * 160 + tok] = f2bf(v);
                }
            }
        }
    }
    __syncthreads();   // the ONLY barrier: Q/K/VT ready for all waves

    // ---- S^T = K · Q^T : st[i][mt] holds S[tok=16*nti+l15][key=16*mt+quad*4+r]
    bf16x8 qb[3];
#pragma unroll
    for (int i = 0; i < 3; ++i) {
        int nti = wave + 4 * i;
        if (nti < 9) qb[i] = ld8h(Qs + (nti * 16 + l15) * 36 + quad * 8);
    }
    f32x4 st[3][9];
#pragma unroll
    for (int mt = 0; mt < 9; ++mt) {
        bf16x8 ka = ld8h(Ks + (mt * 16 + l15) * 36 + quad * 8);
#pragma unroll
        for (int i = 0; i < 3; ++i) {
            int nti = wave + 4 * i;
            st[i][mt] = (f32x4){0.f, 0.f, 0.f, 0.f};
            if (nti < 9)
                st[i][mt] = __builtin_amdgcn_mfma_f32_16x16x32_bf16(
                    ka, qb[i], st[i][mt], 0, 0, 0);
        }
    }

    // ---- + earth bias (biasT layout [key][tok]; 32B-coalesced per quad) ----
    const bf16* bt = biasT + (size_t)(wb * 6 + head) * 20736;
#pragma unroll
    for (int i = 0; i < 3; ++i) {
        int nti = wave + 4 * i;
        if (nti < 9) {
#pragma unroll
            for (int mt = 0; mt < 9; ++mt)
#pragma unroll
                for (int r = 0; r < 4; ++r)
                    st[i][mt][r] += bf2f(bt[(mt * 16 + quad * 4 + r) * 144
                                            + nti * 16 + l15]);
        }
    }

    // ---- softmax: row = (nti,l15); keys spread in-lane (36) x quads (4) ----
#pragma unroll
    for (int i = 0; i < 3; ++i) {
        int nti = wave + 4 * i;
        if (nti < 9) {
            float mx = -1e30f;
#pragma unroll
            for (int mt = 0; mt < 9; ++mt)
#pragma unroll
                for (int r = 0; r < 4; ++r) mx = fmaxf(mx, st[i][mt][r]);
            mx = fmaxf(mx, __shfl_xor(mx, 16, 64));
            mx = fmaxf(mx, __shfl_xor(mx, 32, 64));
            float s = 0.f;
#pragma unroll
            for (int mt = 0; mt < 9; ++mt)
#pragma unroll
                for (int r = 0; r < 4; ++r) {
                    float e = __expf(st[i][mt][r] - mx);
                    st[i][mt][r] = e;
                    s += e;
                }
            s += __shfl_xor(s, 16, 64);
            s += __shfl_xor(s, 32, 64);
            float inv = 1.f / s;
#pragma unroll
            for (int mt = 0; mt < 9; ++mt)
#pragma unroll
                for (int r = 0; r < 4; ++r) st[i][mt][r] *= inv;
        }
    }

    // ---- O = P V : A-frag built in-register via cross-quad exchange ----
    // dst lane (quad) needs P keys 32ks+quad*8+j  ->  tile 2ks+quad/2,
    // src quads {2(quad&1), 2(quad&1)+1}, r = j%4.
    f32x4 oa[3][2];
#pragma unroll
    for (int i = 0; i < 3; ++i)
#pragma unroll
        for (int n2 = 0; n2 < 2; ++n2) oa[i][n2] = (f32x4){0.f, 0.f, 0.f, 0.f};

#pragma unroll
    for (int i = 0; i < 3; ++i) {
        int nti = wave + 4 * i;
        if (nti < 9) {
#pragma unroll
            for (int ks = 0; ks < 5; ++ks) {
                // own packs: A* = tile 2ks, B* = tile 2ks+1 (zero past key 143)
                unsigned A0 = pack2(st[i][2 * ks][0], st[i][2 * ks][1]);
                unsigned A1 = pack2(st[i][2 * ks][2], st[i][2 * ks][3]);
                unsigned B0 = 0u, B1 = 0u;
                if (ks < 4) {
                    B0 = pack2(st[i][2 * ks + 1][0], st[i][2 * ks + 1][1]);
                    B1 = pack2(st[i][2 * ks + 1][2], st[i][2 * ks + 1][3]);
                }
                bool lo2 = quad < 2;
                unsigned Z0 = lo2 ? A0 : B0, Z1 = lo2 ? A1 : B1;
                unsigned Y0 = lo2 ? B0 : A0, Y1 = lo2 ? B1 : A1;
                unsigned s16_0 = __shfl_xor((int)Z0, 16, 64);
                unsigned s16_1 = __shfl_xor((int)Z1, 16, 64);
                unsigned s32_0 = __shfl_xor((int)Y0, 32, 64);
                unsigned s32_1 = __shfl_xor((int)Y1, 32, 64);
                unsigned s48_0 = __shfl_xor((int)Y0, 48, 64);
                unsigned s48_1 = __shfl_xor((int)Y1, 48, 64);
                union { unsigned u[4]; bf16x8 v; } fr;
                fr.u[0] = (quad == 0) ? Z0 : (quad == 1) ? s48_0 : (quad == 2) ? s32_0 : s16_0;
                fr.u[1] = (quad == 0) ? Z1 : (quad == 1) ? s48_1 : (quad == 2) ? s32_1 : s16_1;
                fr.u[2] = (quad == 0) ? s16_0 : (quad == 1) ? s32_0 : (quad == 2) ? s48_0 : Z0;
                fr.u[3] = (quad == 0) ? s16_1 : (quad == 1) ? s32_1 : (quad == 2) ? s48_1 : Z1;
#pragma unroll
                for (int n2 = 0; n2 < 2; ++n2) {
                    bf16x8 vb = *(const bf16x8*)(VTs + (n2 * 16 + l15) * 160
                                                 + ks * 32 + quad * 8);
                    oa[i][n2] = __builtin_amdgcn_mfma_f32_16x16x32_bf16(
                        fr.v, vb, oa[i][n2], 0, 0, 0);
                }
            }
        }
    }

    // ---- store attn_out ----
#pragma unroll
    for (int i = 0; i < 3; ++i) {
        int nti = wave + 4 * i;
        if (nti < 9) {
#pragma unroll
            for (int n2 = 0; n2 < 2; ++n2)
#pragma unroll
                for (int r = 0; r < 4; ++r) {
                    int tok = nti * 16 + quad * 4 + r;
                    attn_out[(size_t)(wi * 144 + tok) * 192 + (head << 5) + n2 * 16 + l15]
                        = f2bf(oa[i][n2][r]);
                }
        }
    }
}

// ---------------------------------------------------------------------------
// Kernel 2 (MFMA): proj + window-reverse/crop + LN1 + residual -> x1
// ---------------------------------------------------------------------------
__global__ __launch_bounds__(256, 2) void proj_mfma_kernel(
    const bf16* __restrict__ attn, const float* __restrict__ proj_w,
    const float* __restrict__ proj_b, const float* __restrict__ xin,
    const float* __restrict__ n1w, const float* __restrict__ n1b,
    bf16* __restrict__ x1out)
{
    // LDS: Xs [128][200] bf16 @0 (51200) | wsum [128][4] @51200 (2048)
    //      wsq [128][4] @53248 (2048) | mean [128] @55296 | rstd [128] @55808
    __shared__ alignas(16) char sm[56320];
    bf16*  Xs     = (bf16*)sm;
    float* wsum   = (float*)(sm + 51200);
    float* wsq    = (float*)(sm + 53248);
    float* mean_s = (float*)(sm + 55296);
    float* rstd_s = (float*)(sm + 55808);

    const int tid  = threadIdx.x;
    const int wave = tid >> 6;
    const int lane = tid & 63;
    const int quad = lane >> 4;
    const int l15  = lane & 15;
    const long tok0 = (long)blockIdx.x * 128;
    const int colw = wave * 48;

    // ---- gather attn rows (window reverse + crop) into Xs ----
    for (int i = tid; i < 128 * 24; i += 256) {
        int r = i / 24, c4 = i - r * 24;
        long l = tok0 + r;
        uint4 v = make_uint4(0u, 0u, 0u, 0u);
        if (l < 131040) {
            int li  = (int)l;
            int z   = li / 16380, rem = li - z * 16380;
            int lat = rem / 180, lon = rem - lat * 180;
            int latp = lat + 2;
            int zw = z >> 1, tz = z & 1;
            int hw = latp / 6, th = latp - hw * 6;
            int wwn = lon / 12, tw = lon - wwn * 12;
            int wi = (zw * 16 + hw) * 15 + wwn;
            int t  = (tz * 6 + th) * 12 + tw;
            v = *(const uint4*)(attn + (size_t)(wi * 144 + t) * 192 + c4 * 8);
        }
        *(uint4*)(Xs + r * 200 + c4 * 8) = v;
    }
    __syncthreads();

    // ---- GEMM: o[nt][mt] = Xs @ proj_w.T (wave's 48-col slice) ----
    f32x4 o[3][8];
#pragma unroll
    for (int nt = 0; nt < 3; ++nt)
#pragma unroll
        for (int mt = 0; mt < 8; ++mt)
            o[nt][mt] = (f32x4){0.f, 0.f, 0.f, 0.f};

#pragma unroll
    for (int ks = 0; ks < 6; ++ks) {
        bf16x8 wfr[3];
#pragma unroll
        for (int nt = 0; nt < 3; ++nt) {
            const float* wp = proj_w + (size_t)(colw + nt * 16 + l15) * 192
                            + ks * 32 + quad * 8;
            float4 lo = *(const float4*)wp;
            float4 hi = *(const float4*)(wp + 4);
            wfr[nt] = pack8(lo, hi);
        }
#pragma unroll
        for (int mt = 0; mt < 8; ++mt) {
            bf16x8 a = *(const bf16x8*)(Xs + (mt * 16 + l15) * 200 + ks * 32 + quad * 8);
#pragma unroll
            for (int nt = 0; nt < 3; ++nt)
                o[nt][mt] = __builtin_amdgcn_mfma_f32_16x16x32_bf16(
                    a, wfr[nt], o[nt][mt], 0, 0, 0);
        }
    }

    // ---- + proj bias ----
    float pbv[3], gw[3], gb[3];
#pragma unroll
    for (int nt = 0; nt < 3; ++nt) {
        int c = colw + nt * 16 + l15;
        pbv[nt] = proj_b[c];
        gw[nt]  = n1w[c];
        gb[nt]  = n1b[c];
    }
#pragma unroll
    for (int nt = 0; nt < 3; ++nt)
#pragma unroll
        for (int mt = 0; mt < 8; ++mt)
#pragma unroll
            for (int r = 0; r < 4; ++r)
                o[nt][mt][r] += pbv[nt];

    // ---- LN1 row stats (cross-wave via LDS) ----
#pragma unroll
    for (int mt = 0; mt < 8; ++mt) {
#pragma unroll
        for (int r = 0; r < 4; ++r) {
            float p = o[0][mt][r] + o[1][mt][r] + o[2][mt][r];
            float q = o[0][mt][r] * o[0][mt][r] + o[1][mt][r] * o[1][mt][r]
                    + o[2][mt][r] * o[2][mt][r];
#pragma unroll
            for (int m_ = 1; m_ < 16; m_ <<= 1) {
                p += __shfl_xor(p, m_, 64);
                q += __shfl_xor(q, m_, 64);
            }
            if (l15 == 0) {
                int row = mt * 16 + quad * 4 + r;
                wsum[row * 4 + wave] = p;
                wsq [row * 4 + wave] = q;
            }
        }
    }
    __syncthreads();
    if (tid < 128) {
        float s  = wsum[tid * 4] + wsum[tid * 4 + 1] + wsum[tid * 4 + 2] + wsum[tid * 4 + 3];
        float ss = wsq [tid * 4] + wsq [tid * 4 + 1] + wsq [tid * 4 + 2] + wsq [tid * 4 + 3];
        float m = s * (1.f / 192.f);
        float var = ss * (1.f / 192.f) - m * m;
        mean_s[tid] = m;
        rstd_s[tid] = rsqrtf(fmaxf(var, 0.f) + 1e-5f);
    }
    __syncthreads();

    // ---- x1 = xin + LN1(proj_out) ----
#pragma unroll
    for (int mt = 0; mt < 8; ++mt) {
#pragma unroll
        for (int r = 0; r < 4; ++r) {
            int row = mt * 16 + quad * 4 + r;
            long tok = tok0 + row;
            if (tok < 131040) {
                float m = mean_s[row], rsd = rstd_s[row];
#pragma unroll
                for (int nt = 0; nt < 3; ++nt) {
                    int c = colw + nt * 16 + l15;
                    float val = (o[nt][mt][r] - m) * rsd * gw[nt] + gb[nt]
                              + xin[(size_t)tok * 192 + c];
                    x1out[(size_t)tok * 192 + c] = f2bf(val);
                }
            }
        }
    }
}

// ---------------------------------------------------------------------------
// Prep C: convert w1/w2 fp32 -> bf16 (unchanged)
// ---------------------------------------------------------------------------
__global__ __launch_bounds__(256) void prep_weights(
    const float* __restrict__ w1, const float* __restrict__ w2,
    unsigned int* __restrict__ w1b, unsigned int* __restrict__ w2b)
{
    int i = blockIdx.x * 256 + threadIdx.x;
    if (i < 73728) {
        w1b[i] = pack2(w1[2 * i], w1[2 * i + 1]);
    } else {
        int j = i - 73728;
        w2b[j] = pack2(w2[2 * j], w2[2 * j + 1]);
    }
}

// ---------------------------------------------------------------------------
// Kernel 3 (MFMA): fused MLP + LN2 + residual (unchanged)
// ---------------------------------------------------------------------------
__global__ __launch_bounds__(256, 2) void mlp_mfma_kernel(
    const bf16* __restrict__ x1, const bf16* __restrict__ w1b,
    const float* __restrict__ b1, const bf16* __restrict__ w2b,
    const float* __restrict__ b2, const float* __restrict__ n2w,
    const float* __restrict__ n2b, float* __restrict__ out)
{
    __shared__ alignas(16) char sm[53760];
    bf16*  Xs     = (bf16*)sm;
    bf16*  Hs     = (bf16*)(sm + 25600);
    float* wsum   = (float*)(sm + 51200);
    float* wsq    = (float*)(sm + 52224);
    float* mean_s = (float*)(sm + 53248);
    float* rstd_s = (float*)(sm + 53504);

    const int tid  = threadIdx.x;
    const int wave = tid >> 6;
    const int lane = tid & 63;
    const int quad = lane >> 4;
    const int l15  = lane & 15;
    const long tok0 = (long)blockIdx.x * 64;
    const int colw = wave * 48;

    for (int i = tid; i < 64 * 24; i += 256) {
        int r = i / 24, c8 = i - r * 24;
        uint4 v = make_uint4(0u, 0u, 0u, 0u);
        if (tok0 + r < 131040)
            v = *(const uint4*)(x1 + (tok0 + r) * 192 + (size_t)c8 * 8);
        *(uint4*)(Xs + r * 200 + c8 * 8) = v;
    }
    __syncthreads();

    bf16x8 af[4][6];
#pragma unroll
    for (int mt = 0; mt < 4; ++mt)
#pragma unroll
        for (int ks = 0; ks < 6; ++ks)
            af[mt][ks] = *(const bf16x8*)(Xs + (mt * 16 + l15) * 200 + ks * 32 + quad * 8);

    f32x4 o[3][4];
#pragma unroll
    for (int nt = 0; nt < 3; ++nt)
#pragma unroll
        for (int mt = 0; mt < 4; ++mt)
            o[nt][mt] = (f32x4){0.f, 0.f, 0.f, 0.f};

    for (int nc = 0; nc < 4; ++nc) {
        f32x4 g[3][4];
#pragma unroll
        for (int nt = 0; nt < 3; ++nt)
#pragma unroll
            for (int mt = 0; mt < 4; ++mt)
                g[nt][mt] = (f32x4){0.f, 0.f, 0.f, 0.f};
        const int h0 = nc * 192 + colw;
#pragma unroll
        for (int ks = 0; ks < 6; ++ks) {
            bf16x8 bfr[3];
#pragma unroll
            for (int nt = 0; nt < 3; ++nt)
                bfr[nt] = *(const bf16x8*)(w1b + (size_t)(h0 + nt * 16 + l15) * 192 + ks * 32 + quad * 8);
#pragma unroll
            for (int nt = 0; nt < 3; ++nt)
#pragma unroll
                for (int mt = 0; mt < 4; ++mt)
                    g[nt][mt] = __builtin_amdgcn_mfma_f32_16x16x32_bf16(
                        af[mt][ks], bfr[nt], g[nt][mt], 0, 0, 0);
        }
        __syncthreads();

#pragma unroll
        for (int nt = 0; nt < 3; ++nt) {
            float bb = b1[h0 + nt * 16 + l15];
            int hcol = colw + nt * 16 + l15;
#pragma unroll
            for (int mt = 0; mt < 4; ++mt) {
#pragma unroll
                for (int r = 0; r < 4; ++r) {
                    float v = g[nt][mt][r] + bb;
                    float u = v * (0.7978845608028654f + 0.035677408136300125f * v * v);
                    float e = __expf(2.f * u);
                    float t = 1.f - 2.f / (e + 1.f);
                    float gl = 0.5f * v * (1.f + t);
                    Hs[(mt * 16 + quad * 4 + r) * 200 + hcol] = f2bf(gl);
                }
            }
        }
        __syncthreads();

#pragma unroll
        for (int ks = 0; ks < 6; ++ks) {
            bf16x8 hf[4];
#pragma unroll
            for (int mt = 0; mt < 4; ++mt)
                hf[mt] = *(const bf16x8*)(Hs + (mt * 16 + l15) * 200 + ks * 32 + quad * 8);
            bf16x8 wf[3];
#pragma unroll
            for (int nt = 0; nt < 3; ++nt)
                wf[nt] = *(const bf16x8*)(w2b + (size_t)(colw + nt * 16 + l15) * 768 + nc * 192 + ks * 32 + quad * 8);
#pragma unroll
            for (int nt = 0; nt < 3; ++nt)
#pragma unroll
                for (int mt = 0; mt < 4; ++mt)
                    o[nt][mt] = __builtin_amdgcn_mfma_f32_16x16x32_bf16(
                        hf[mt], wf[nt], o[nt][mt], 0, 0, 0);
        }
    }

    float b2v[3], gw[3], gb[3];
#pragma unroll
    for (int nt = 0; nt < 3; ++nt) {
        int c = colw + nt * 16 + l15;
        b2v[nt] = b2[c];
        gw[nt] = n2w[c];
        gb[nt] = n2b[c];
    }
#pragma unroll
    for (int nt = 0; nt < 3; ++nt)
#pragma unroll
        for (int mt = 0; mt < 4; ++mt)
#pragma unroll
            for (int r = 0; r < 4; ++r)
                o[nt][mt][r] += b2v[nt];

#pragma unroll
    for (int mt = 0; mt < 4; ++mt) {
#pragma unroll
        for (int r = 0; r < 4; ++r) {
            float p = o[0][mt][r] + o[1][mt][r] + o[2][mt][r];
            float q = o[0][mt][r] * o[0][mt][r] + o[1][mt][r] * o[1][mt][r]
                    + o[2][mt][r] * o[2][mt][r];
#pragma unroll
            for (int m_ = 1; m_ < 16; m_ <<= 1) {
                p += __shfl_xor(p, m_, 64);
                q += __shfl_xor(q, m_, 64);
            }
            if (l15 == 0) {
                int row = mt * 16 + quad * 4 + r;
                wsum[row * 4 + wave] = p;
                wsq [row * 4 + wave] = q;
            }
        }
    }
    __syncthreads();
    if (tid < 64) {
        float s  = wsum[tid * 4] + wsum[tid * 4 + 1] + wsum[tid * 4 + 2] + wsum[tid * 4 + 3];
        float ss = wsq [tid * 4] + wsq [tid * 4 + 1] + wsq [tid * 4 + 2] + wsq [tid * 4 + 3];
        float m = s * (1.f / 192.f);
        float var = ss * (1.f / 192.f) - m * m;
        mean_s[tid] = m;
        rstd_s[tid] = rsqrtf(fmaxf(var, 0.f) + 1e-5f);
    }
    __syncthreads();

#pragma unroll
    for (int mt = 0; mt < 4; ++mt) {
#pragma unroll
        for (int r = 0; r < 4; ++r) {
            int row = mt * 16 + quad * 4 + r;
            long tok = tok0 + row;
            if (tok < 131040) {
                float m = mean_s[row], rsd = rstd_s[row];
#pragma unroll
                for (int nt = 0; nt < 3; ++nt) {
                    int c = colw + nt * 16 + l15;
                    float val = (o[nt][mt][r] - m) * rsd * gw[nt] + gb[nt]
                              + bf2f(Xs[row * 200 + c]);
                    out[tok * 192 + c] = val;
                }
            }
        }
    }
}

// ---------------------------------------------------------------------------
extern "C" void kernel_launch(void* const* d_in, const int* in_sizes, int n_in,
                              void* d_out, int out_size, void* d_ws, size_t ws_size,
                              hipStream_t stream) {
    (void)in_sizes; (void)n_in; (void)out_size; (void)ws_size;
    const float* x          = (const float*)d_in[0];
    const float* qkv_w      = (const float*)d_in[1];
    const float* qkv_b      = (const float*)d_in[2];
    const float* proj_w     = (const float*)d_in[3];
    const float* proj_b     = (const float*)d_in[4];
    const float* bias_table = (const float*)d_in[5];
    const float* n1w        = (const float*)d_in[6];
    const float* n1b        = (const float*)d_in[7];
    const float* n2w        = (const float*)d_in[8];
    const float* n2b        = (const float*)d_in[9];
    const float* w1         = (const float*)d_in[10];
    const float* b1         = (const float*)d_in[11];
    const float* w2         = (const float*)d_in[12];
    const float* b2         = (const float*)d_in[13];
    float* out = (float*)d_out;

    // ws layout:
    //  [0, 53084160)            attn rows bf16 (dead after proj; start reused for w1b/w2b)
    //  [53084160, +50319360)    x1 bf16 (written by proj). BEFORE proj runs, this
    //                           region hosts attn prep data (read only by attn):
    //    qkv_wb @53084160 (221184 B) | qkv_bb @53305344 (2304 B) | biasT @53307648 (15925248 B)
    bf16*  attn_ws = (bf16*)d_ws;
    bf16*  x1_ws   = (bf16*)((char*)d_ws + 53084160);
    bf16*  w1b     = (bf16*)d_ws;
    bf16*  w2b     = (bf16*)((char*)d_ws + 294912);
    bf16*  qkv_wb  = (bf16*)((char*)d_ws + 53084160);
    float* qkv_bb  = (float*)((char*)d_ws + 53305344);
    bf16*  biasT   = (bf16*)((char*)d_ws + 53307648);

    prep_attn_w<<<432, 256, 0, stream>>>(qkv_w, qkv_b, qkv_wb, qkv_bb);
    prep_bias<<<31104, 256, 0, stream>>>(bias_table, biasT);
    attn_mfma_kernel<<<5760, 256, 0, stream>>>(x, qkv_wb, qkv_bb, biasT, attn_ws);
    proj_mfma_kernel<<<1024, 256, 0, stream>>>(attn_ws, proj_w, proj_b, x, n1w, n1b, x1_ws);
    prep_weights<<<576, 256, 0, stream>>>(w1, w2, (unsigned int*)w1b, (unsigned int*)w2b);
    mlp_mfma_kernel<<<2048, 256, 0, stream>>>(x1_ws, w1b, b1, w2b, b2, n2w, n2b, out);
}

// Round 4
// 756.154 us; speedup vs baseline: 1.0363x; 1.0363x over previous
//
#include <hip/hip_runtime.h>
#include <hip/hip_bf16.h>

typedef __hip_bfloat16 bf16;
#define DEVI __device__ __forceinline__

typedef __bf16 bf16x8 __attribute__((ext_vector_type(8)));
typedef __bf16 bf16x4 __attribute__((ext_vector_type(4)));
typedef float  f32x4  __attribute__((ext_vector_type(4)));

DEVI float bf2f(bf16 v) { return __bfloat162float(v); }
DEVI bf16 f2bf(float v) { return __float2bfloat16(v); }

DEVI unsigned short bfbits(float x) {
    bf16 h = __float2bfloat16(x);
    return *reinterpret_cast<unsigned short*>(&h);
}
DEVI unsigned int pack2(float x, float y) {
    return (unsigned int)bfbits(x) | ((unsigned int)bfbits(y) << 16);
}
DEVI bf16x8 pack8(float4 lo, float4 hi) {
    union { unsigned int u[4]; bf16x8 v; } z;
    z.u[0] = pack2(lo.x, lo.y); z.u[1] = pack2(lo.z, lo.w);
    z.u[2] = pack2(hi.x, hi.y); z.u[3] = pack2(hi.z, hi.w);
    return z.v;
}
// LDS bf16x8 load from an 8-byte-aligned (not 16) address: two b64 halves
DEVI bf16x8 ld8h(const bf16* p) {
    bf16x4 lo = *(const bf16x4*)p;
    bf16x4 hi = *(const bf16x4*)(p + 4);
    return __builtin_shufflevector(lo, hi, 0, 1, 2, 3, 4, 5, 6, 7);
}

// ---------------------------------------------------------------------------
// Prep A: reorder qkv weights per head into [h][96][192] bf16, fold 1/sqrt(32)
// into the q rows and q bias. qkv_bb fp32 [576] in [h][96] order.
// ---------------------------------------------------------------------------
__global__ __launch_bounds__(256) void prep_attn_w(
    const float* __restrict__ qkv_w, const float* __restrict__ qkv_b,
    bf16* __restrict__ qkv_wb, float* __restrict__ qkv_bb)
{
    const float scale = 0.17677669529663687f;
    int idx = blockIdx.x * 256 + threadIdx.x;
    if (idx < 110592) {
        int c = idx % 192, d = idx / 192;
        int h = d / 96, q2 = d - h * 96, seg = q2 >> 5, rr = q2 & 31;
        float v = qkv_w[(size_t)(seg * 192 + h * 32 + rr) * 192 + c];
        if (seg == 0) v *= scale;
        qkv_wb[idx] = f2bf(v);
    }
    if (idx < 576) {
        int h = idx / 96, q2 = idx - h * 96, seg = q2 >> 5, rr = q2 & 31;
        float b = qkv_b[seg * 192 + h * 32 + rr];
        if (seg == 0) b *= scale;
        qkv_bb[idx] = b;
    }
}

// ---------------------------------------------------------------------------
// Prep B: earth bias tiles, TRANSPOSED layout biasT[wb][h][key][tok] bf16
// (so the attn kernel's gather bt[key*144+tok] is lane-contiguous in tok).
// ---------------------------------------------------------------------------
__global__ __launch_bounds__(256) void prep_bias(
    const float* __restrict__ bias_table, bf16* __restrict__ biasT)
{
    int idx = blockIdx.x * 256 + threadIdx.x;
    if (idx >= 7962624) return;
    int t = idx % 144;             // tok (query)
    int k = (idx / 144) % 144;     // key
    int r2 = idx / 20736;
    int h = r2 % 6, wb = r2 / 6;
    int tzq = t / 72, thq = (t / 12) % 6, twq = t % 12;
    int tzk = k / 72, thk = (k / 12) % 6, twk = k % 12;
    int bidx = (tzq + 2 * tzk) * 828 + (thq + 6 * thk) * 23 + (twq - twk + 11);
    biasT[idx] = f2bf(bias_table[(size_t)(bidx * 64 + wb) * 6 + h]);
}

// ---------------------------------------------------------------------------
// Kernel 1 (MFMA): windowed attention, one block per (window, head), 4 waves.
// Swapped QK^T (S^T = K·Q^T), in-register softmax, in-register P->A-frag for
// PV. REGISTER-LEAN version: each wave pushes its query-tile groups through
// the full S->softmax->PV->store pipeline SEQUENTIALLY (st[9] live, not
// st[3][9]); QKV loads weights per (i,nt) instead of holding af[3][6].
// Peak regs ~96 -> 4-5 waves/SIMD; LDS 30976 B -> 5 blocks/CU.
// ---------------------------------------------------------------------------
__global__ __launch_bounds__(256, 4) void attn_mfma_kernel(
    const float* __restrict__ x, const bf16* __restrict__ qkv_wb,
    const float* __restrict__ qkv_bb, const bf16* __restrict__ biasT,
    bf16* __restrict__ attn_out)
{
    // LDS: Qs [144][36] @0 (10368) | Ks [144][36] @10368 | VTs [32][160] @20736
    __shared__ alignas(16) char sm[30976];
    bf16* Qs  = (bf16*)sm;
    bf16* Ks  = (bf16*)(sm + 10368);
    bf16* VTs = (bf16*)(sm + 20736);

    const int tid  = threadIdx.x;
    const int wave = tid >> 6;
    const int lane = tid & 63;
    const int quad = lane >> 4;
    const int l15  = lane & 15;

    // XCD-chunked swizzle: 5760 blocks = 8 XCDs x 720; head-fastest order.
    const int bid     = blockIdx.x;
    const int logical = (bid & 7) * 720 + (bid >> 3);
    const int wi      = logical / 6;
    const int head    = logical % 6;
    const int ww_  = wi % 15;
    const int hw   = (wi / 15) % 16;
    const int zw   = wi / 240;
    const int wb   = zw * 16 + hw;

    // zero VT pad cols [144,160)
    for (int i = tid; i < 512; i += 256) {
        int d = i >> 4, c = i & 15;
        VTs[d * 160 + 144 + c] = f2bf(0.f);
    }

    // ---- QKV GEMM, register-lean: i outer, af[6] per group, bw reloaded ----
    for (int i = 0; i < 3; ++i) {
        int mt = wave + 4 * i;
        if (mt < 9) {
            int t  = mt * 16 + l15;
            int tz = t / 72, rr = t - tz * 72;
            int th = rr / 12, tw = rr - th * 12;
            int lat = hw * 6 + th - 2;
            bool valid = (lat >= 0 && lat < 91);
            size_t base = ((size_t)((zw * 2 + tz) * 91 + (valid ? lat : 0)) * 180
                           + ww_ * 12 + tw) * 192;
            bf16x8 af[6];
#pragma unroll
            for (int ks = 0; ks < 6; ++ks) {
                float4 lo = make_float4(0.f, 0.f, 0.f, 0.f);
                float4 hi = make_float4(0.f, 0.f, 0.f, 0.f);
                if (valid) {
                    lo = *(const float4*)(x + base + ks * 32 + quad * 8);
                    hi = *(const float4*)(x + base + ks * 32 + quad * 8 + 4);
                }
                af[ks] = pack8(lo, hi);
            }
            for (int nt = 0; nt < 6; ++nt) {
                const bf16* wrow = qkv_wb + (size_t)(head * 96 + nt * 16 + l15) * 192;
                bf16x8 bw[6];
#pragma unroll
                for (int ks = 0; ks < 6; ++ks)
                    bw[ks] = *(const bf16x8*)(wrow + ks * 32 + quad * 8);
                float bias = qkv_bb[head * 96 + nt * 16 + l15];

                f32x4 acc = (f32x4){0.f, 0.f, 0.f, 0.f};
#pragma unroll
                for (int ks = 0; ks < 6; ++ks)
                    acc = __builtin_amdgcn_mfma_f32_16x16x32_bf16(
                        af[ks], bw[ks], acc, 0, 0, 0);
#pragma unroll
                for (int r = 0; r < 4; ++r) {
                    float v = acc[r] + bias;
                    int tok = mt * 16 + quad * 4 + r;
                    if (nt < 2)      Qs[tok * 36 + nt * 16 + l15] = f2bf(v);
                    else if (nt < 4) Ks[tok * 36 + (nt - 2) * 16 + l15] = f2bf(v);
                    else             VTs[((nt - 4) * 16 + l15) * 160 + tok] = f2bf(v);
                }
            }
        }
    }
    __syncthreads();   // the ONLY barrier: Q/K/VT ready for all waves

    const bf16* bt = biasT + (size_t)(wb * 6 + head) * 20736;

    // ---- per query-tile group: S^T -> bias -> softmax -> PV -> store ----
    for (int i = 0; i < 3; ++i) {
        int nti = wave + 4 * i;
        if (nti >= 9) continue;   // no barriers below; safe

        bf16x8 qb = ld8h(Qs + (nti * 16 + l15) * 36 + quad * 8);

        // S^T = K · Q^T : st[mt] holds S[tok=16*nti+l15][key=16*mt+quad*4+r]
        f32x4 st[9];
#pragma unroll
        for (int mt = 0; mt < 9; ++mt) {
            bf16x8 ka = ld8h(Ks + (mt * 16 + l15) * 36 + quad * 8);
            st[mt] = (f32x4){0.f, 0.f, 0.f, 0.f};
            st[mt] = __builtin_amdgcn_mfma_f32_16x16x32_bf16(
                ka, qb, st[mt], 0, 0, 0);
        }

        // + earth bias (biasT layout [key][tok]; 32B-coalesced per quad)
#pragma unroll
        for (int mt = 0; mt < 9; ++mt)
#pragma unroll
            for (int r = 0; r < 4; ++r)
                st[mt][r] += bf2f(bt[(mt * 16 + quad * 4 + r) * 144
                                     + nti * 16 + l15]);

        // softmax: row = (nti,l15); keys spread in-lane (36) x quads (4)
        float mx = -1e30f;
#pragma unroll
        for (int mt = 0; mt < 9; ++mt)
#pragma unroll
            for (int r = 0; r < 4; ++r) mx = fmaxf(mx, st[mt][r]);
        mx = fmaxf(mx, __shfl_xor(mx, 16, 64));
        mx = fmaxf(mx, __shfl_xor(mx, 32, 64));
        float s = 0.f;
#pragma unroll
        for (int mt = 0; mt < 9; ++mt)
#pragma unroll
            for (int r = 0; r < 4; ++r) {
                float e = __expf(st[mt][r] - mx);
                st[mt][r] = e;
                s += e;
            }
        s += __shfl_xor(s, 16, 64);
        s += __shfl_xor(s, 32, 64);
        float inv = 1.f / s;
#pragma unroll
        for (int mt = 0; mt < 9; ++mt)
#pragma unroll
            for (int r = 0; r < 4; ++r) st[mt][r] *= inv;

        // O = P V : A-frag built in-register via cross-quad exchange
        f32x4 oa[2];
        oa[0] = (f32x4){0.f, 0.f, 0.f, 0.f};
        oa[1] = (f32x4){0.f, 0.f, 0.f, 0.f};
#pragma unroll
        for (int ks = 0; ks < 5; ++ks) {
            unsigned A0 = pack2(st[2 * ks][0], st[2 * ks][1]);
            unsigned A1 = pack2(st[2 * ks][2], st[2 * ks][3]);
            unsigned B0 = 0u, B1 = 0u;
            if (ks < 4) {
                B0 = pack2(st[2 * ks + 1][0], st[2 * ks + 1][1]);
                B1 = pack2(st[2 * ks + 1][2], st[2 * ks + 1][3]);
            }
            bool lo2 = quad < 2;
            unsigned Z0 = lo2 ? A0 : B0, Z1 = lo2 ? A1 : B1;
            unsigned Y0 = lo2 ? B0 : A0, Y1 = lo2 ? B1 : A1;
            unsigned s16_0 = __shfl_xor((int)Z0, 16, 64);
            unsigned s16_1 = __shfl_xor((int)Z1, 16, 64);
            unsigned s32_0 = __shfl_xor((int)Y0, 32, 64);
            unsigned s32_1 = __shfl_xor((int)Y1, 32, 64);
            unsigned s48_0 = __shfl_xor((int)Y0, 48, 64);
            unsigned s48_1 = __shfl_xor((int)Y1, 48, 64);
            union { unsigned u[4]; bf16x8 v; } fr;
            fr.u[0] = (quad == 0) ? Z0 : (quad == 1) ? s48_0 : (quad == 2) ? s32_0 : s16_0;
            fr.u[1] = (quad == 0) ? Z1 : (quad == 1) ? s48_1 : (quad == 2) ? s32_1 : s16_1;
            fr.u[2] = (quad == 0) ? s16_0 : (quad == 1) ? s32_0 : (quad == 2) ? s48_0 : Z0;
            fr.u[3] = (quad == 0) ? s16_1 : (quad == 1) ? s32_1 : (quad == 2) ? s48_1 : Z1;
#pragma unroll
            for (int n2 = 0; n2 < 2; ++n2) {
                bf16x8 vb = *(const bf16x8*)(VTs + (n2 * 16 + l15) * 160
                                             + ks * 32 + quad * 8);
                oa[n2] = __builtin_amdgcn_mfma_f32_16x16x32_bf16(
                    fr.v, vb, oa[n2], 0, 0, 0);
            }
        }

        // store attn_out for this query-tile group
#pragma unroll
        for (int n2 = 0; n2 < 2; ++n2)
#pragma unroll
            for (int r = 0; r < 4; ++r) {
                int tok = nti * 16 + quad * 4 + r;
                attn_out[(size_t)(wi * 144 + tok) * 192 + (head << 5) + n2 * 16 + l15]
                    = f2bf(oa[n2][r]);
            }
    }
}

// ---------------------------------------------------------------------------
// Kernel 2 (MFMA): proj + window-reverse/crop + LN1 + residual -> x1
// ---------------------------------------------------------------------------
__global__ __launch_bounds__(256, 2) void proj_mfma_kernel(
    const bf16* __restrict__ attn, const float* __restrict__ proj_w,
    const float* __restrict__ proj_b, const float* __restrict__ xin,
    const float* __restrict__ n1w, const float* __restrict__ n1b,
    bf16* __restrict__ x1out)
{
    // LDS: Xs [128][200] bf16 @0 (51200) | wsum [128][4] @51200 (2048)
    //      wsq [128][4] @53248 (2048) | mean [128] @55296 | rstd [128] @55808
    __shared__ alignas(16) char sm[56320];
    bf16*  Xs     = (bf16*)sm;
    float* wsum   = (float*)(sm + 51200);
    float* wsq    = (float*)(sm + 53248);
    float* mean_s = (float*)(sm + 55296);
    float* rstd_s = (float*)(sm + 55808);

    const int tid  = threadIdx.x;
    const int wave = tid >> 6;
    const int lane = tid & 63;
    const int quad = lane >> 4;
    const int l15  = lane & 15;
    const long tok0 = (long)blockIdx.x * 128;
    const int colw = wave * 48;

    // ---- gather attn rows (window reverse + crop) into Xs ----
    for (int i = tid; i < 128 * 24; i += 256) {
        int r = i / 24, c4 = i - r * 24;
        long l = tok0 + r;
        uint4 v = make_uint4(0u, 0u, 0u, 0u);
        if (l < 131040) {
            int li  = (int)l;
            int z   = li / 16380, rem = li - z * 16380;
            int lat = rem / 180, lon = rem - lat * 180;
            int latp = lat + 2;
            int zw = z >> 1, tz = z & 1;
            int hw = latp / 6, th = latp - hw * 6;
            int wwn = lon / 12, tw = lon - wwn * 12;
            int wi = (zw * 16 + hw) * 15 + wwn;
            int t  = (tz * 6 + th) * 12 + tw;
            v = *(const uint4*)(attn + (size_t)(wi * 144 + t) * 192 + c4 * 8);
        }
        *(uint4*)(Xs + r * 200 + c4 * 8) = v;
    }
    __syncthreads();

    // ---- GEMM: o[nt][mt] = Xs @ proj_w.T (wave's 48-col slice) ----
    f32x4 o[3][8];
#pragma unroll
    for (int nt = 0; nt < 3; ++nt)
#pragma unroll
        for (int mt = 0; mt < 8; ++mt)
            o[nt][mt] = (f32x4){0.f, 0.f, 0.f, 0.f};

#pragma unroll
    for (int ks = 0; ks < 6; ++ks) {
        bf16x8 wfr[3];
#pragma unroll
        for (int nt = 0; nt < 3; ++nt) {
            const float* wp = proj_w + (size_t)(colw + nt * 16 + l15) * 192
                            + ks * 32 + quad * 8;
            float4 lo = *(const float4*)wp;
            float4 hi = *(const float4*)(wp + 4);
            wfr[nt] = pack8(lo, hi);
        }
#pragma unroll
        for (int mt = 0; mt < 8; ++mt) {
            bf16x8 a = *(const bf16x8*)(Xs + (mt * 16 + l15) * 200 + ks * 32 + quad * 8);
#pragma unroll
            for (int nt = 0; nt < 3; ++nt)
                o[nt][mt] = __builtin_amdgcn_mfma_f32_16x16x32_bf16(
                    a, wfr[nt], o[nt][mt], 0, 0, 0);
        }
    }

    // ---- + proj bias ----
    float pbv[3], gw[3], gb[3];
#pragma unroll
    for (int nt = 0; nt < 3; ++nt) {
        int c = colw + nt * 16 + l15;
        pbv[nt] = proj_b[c];
        gw[nt]  = n1w[c];
        gb[nt]  = n1b[c];
    }
#pragma unroll
    for (int nt = 0; nt < 3; ++nt)
#pragma unroll
        for (int mt = 0; mt < 8; ++mt)
#pragma unroll
            for (int r = 0; r < 4; ++r)
                o[nt][mt][r] += pbv[nt];

    // ---- LN1 row stats (cross-wave via LDS) ----
#pragma unroll
    for (int mt = 0; mt < 8; ++mt) {
#pragma unroll
        for (int r = 0; r < 4; ++r) {
            float p = o[0][mt][r] + o[1][mt][r] + o[2][mt][r];
            float q = o[0][mt][r] * o[0][mt][r] + o[1][mt][r] * o[1][mt][r]
                    + o[2][mt][r] * o[2][mt][r];
#pragma unroll
            for (int m_ = 1; m_ < 16; m_ <<= 1) {
                p += __shfl_xor(p, m_, 64);
                q += __shfl_xor(q, m_, 64);
            }
            if (l15 == 0) {
                int row = mt * 16 + quad * 4 + r;
                wsum[row * 4 + wave] = p;
                wsq [row * 4 + wave] = q;
            }
        }
    }
    __syncthreads();
    if (tid < 128) {
        float s  = wsum[tid * 4] + wsum[tid * 4 + 1] + wsum[tid * 4 + 2] + wsum[tid * 4 + 3];
        float ss = wsq [tid * 4] + wsq [tid * 4 + 1] + wsq [tid * 4 + 2] + wsq [tid * 4 + 3];
        float m = s * (1.f / 192.f);
        float var = ss * (1.f / 192.f) - m * m;
        mean_s[tid] = m;
        rstd_s[tid] = rsqrtf(fmaxf(var, 0.f) + 1e-5f);
    }
    __syncthreads();

    // ---- x1 = xin + LN1(proj_out) ----
#pragma unroll
    for (int mt = 0; mt < 8; ++mt) {
#pragma unroll
        for (int r = 0; r < 4; ++r) {
            int row = mt * 16 + quad * 4 + r;
            long tok = tok0 + row;
            if (tok < 131040) {
                float m = mean_s[row], rsd = rstd_s[row];
#pragma unroll
                for (int nt = 0; nt < 3; ++nt) {
                    int c = colw + nt * 16 + l15;
                    float val = (o[nt][mt][r] - m) * rsd * gw[nt] + gb[nt]
                              + xin[(size_t)tok * 192 + c];
                    x1out[(size_t)tok * 192 + c] = f2bf(val);
                }
            }
        }
    }
}

// ---------------------------------------------------------------------------
// Prep C: convert w1/w2 fp32 -> bf16 (unchanged)
// ---------------------------------------------------------------------------
__global__ __launch_bounds__(256) void prep_weights(
    const float* __restrict__ w1, const float* __restrict__ w2,
    unsigned int* __restrict__ w1b, unsigned int* __restrict__ w2b)
{
    int i = blockIdx.x * 256 + threadIdx.x;
    if (i < 73728) {
        w1b[i] = pack2(w1[2 * i], w1[2 * i + 1]);
    } else {
        int j = i - 73728;
        w2b[j] = pack2(w2[2 * j], w2[2 * j + 1]);
    }
}

// ---------------------------------------------------------------------------
// Kernel 3 (MFMA): fused MLP + LN2 + residual (unchanged)
// ---------------------------------------------------------------------------
__global__ __launch_bounds__(256, 2) void mlp_mfma_kernel(
    const bf16* __restrict__ x1, const bf16* __restrict__ w1b,
    const float* __restrict__ b1, const bf16* __restrict__ w2b,
    const float* __restrict__ b2, const float* __restrict__ n2w,
    const float* __restrict__ n2b, float* __restrict__ out)
{
    __shared__ alignas(16) char sm[53760];
    bf16*  Xs     = (bf16*)sm;
    bf16*  Hs     = (bf16*)(sm + 25600);
    float* wsum   = (float*)(sm + 51200);
    float* wsq    = (float*)(sm + 52224);
    float* mean_s = (float*)(sm + 53248);
    float* rstd_s = (float*)(sm + 53504);

    const int tid  = threadIdx.x;
    const int wave = tid >> 6;
    const int lane = tid & 63;
    const int quad = lane >> 4;
    const int l15  = lane & 15;
    const long tok0 = (long)blockIdx.x * 64;
    const int colw = wave * 48;

    for (int i = tid; i < 64 * 24; i += 256) {
        int r = i / 24, c8 = i - r * 24;
        uint4 v = make_uint4(0u, 0u, 0u, 0u);
        if (tok0 + r < 131040)
            v = *(const uint4*)(x1 + (tok0 + r) * 192 + (size_t)c8 * 8);
        *(uint4*)(Xs + r * 200 + c8 * 8) = v;
    }
    __syncthreads();

    bf16x8 af[4][6];
#pragma unroll
    for (int mt = 0; mt < 4; ++mt)
#pragma unroll
        for (int ks = 0; ks < 6; ++ks)
            af[mt][ks] = *(const bf16x8*)(Xs + (mt * 16 + l15) * 200 + ks * 32 + quad * 8);

    f32x4 o[3][4];
#pragma unroll
    for (int nt = 0; nt < 3; ++nt)
#pragma unroll
        for (int mt = 0; mt < 4; ++mt)
            o[nt][mt] = (f32x4){0.f, 0.f, 0.f, 0.f};

    for (int nc = 0; nc < 4; ++nc) {
        f32x4 g[3][4];
#pragma unroll
        for (int nt = 0; nt < 3; ++nt)
#pragma unroll
            for (int mt = 0; mt < 4; ++mt)
                g[nt][mt] = (f32x4){0.f, 0.f, 0.f, 0.f};
        const int h0 = nc * 192 + colw;
#pragma unroll
        for (int ks = 0; ks < 6; ++ks) {
            bf16x8 bfr[3];
#pragma unroll
            for (int nt = 0; nt < 3; ++nt)
                bfr[nt] = *(const bf16x8*)(w1b + (size_t)(h0 + nt * 16 + l15) * 192 + ks * 32 + quad * 8);
#pragma unroll
            for (int nt = 0; nt < 3; ++nt)
#pragma unroll
                for (int mt = 0; mt < 4; ++mt)
                    g[nt][mt] = __builtin_amdgcn_mfma_f32_16x16x32_bf16(
                        af[mt][ks], bfr[nt], g[nt][mt], 0, 0, 0);
        }
        __syncthreads();

#pragma unroll
        for (int nt = 0; nt < 3; ++nt) {
            float bb = b1[h0 + nt * 16 + l15];
            int hcol = colw + nt * 16 + l15;
#pragma unroll
            for (int mt = 0; mt < 4; ++mt) {
#pragma unroll
                for (int r = 0; r < 4; ++r) {
                    float v = g[nt][mt][r] + bb;
                    float u = v * (0.7978845608028654f + 0.035677408136300125f * v * v);
                    float e = __expf(2.f * u);
                    float t = 1.f - 2.f / (e + 1.f);
                    float gl = 0.5f * v * (1.f + t);
                    Hs[(mt * 16 + quad * 4 + r) * 200 + hcol] = f2bf(gl);
                }
            }
        }
        __syncthreads();

#pragma unroll
        for (int ks = 0; ks < 6; ++ks) {
            bf16x8 hf[4];
#pragma unroll
            for (int mt = 0; mt < 4; ++mt)
                hf[mt] = *(const bf16x8*)(Hs + (mt * 16 + l15) * 200 + ks * 32 + quad * 8);
            bf16x8 wf[3];
#pragma unroll
            for (int nt = 0; nt < 3; ++nt)
                wf[nt] = *(const bf16x8*)(w2b + (size_t)(colw + nt * 16 + l15) * 768 + nc * 192 + ks * 32 + quad * 8);
#pragma unroll
            for (int nt = 0; nt < 3; ++nt)
#pragma unroll
                for (int mt = 0; mt < 4; ++mt)
                    o[nt][mt] = __builtin_amdgcn_mfma_f32_16x16x32_bf16(
                        hf[mt], wf[nt], o[nt][mt], 0, 0, 0);
        }
    }

    float b2v[3], gw[3], gb[3];
#pragma unroll
    for (int nt = 0; nt < 3; ++nt) {
        int c = colw + nt * 16 + l15;
        b2v[nt] = b2[c];
        gw[nt] = n2w[c];
        gb[nt] = n2b[c];
    }
#pragma unroll
    for (int nt = 0; nt < 3; ++nt)
#pragma unroll
        for (int mt = 0; mt < 4; ++mt)
#pragma unroll
            for (int r = 0; r < 4; ++r)
                o[nt][mt][r] += b2v[nt];

#pragma unroll
    for (int mt = 0; mt < 4; ++mt) {
#pragma unroll
        for (int r = 0; r < 4; ++r) {
            float p = o[0][mt][r] + o[1][mt][r] + o[2][mt][r];
            float q = o[0][mt][r] * o[0][mt][r] + o[1][mt][r] * o[1][mt][r]
                    + o[2][mt][r] * o[2][mt][r];
#pragma unroll
            for (int m_ = 1; m_ < 16; m_ <<= 1) {
                p += __shfl_xor(p, m_, 64);
                q += __shfl_xor(q, m_, 64);
            }
            if (l15 == 0) {
                int row = mt * 16 + quad * 4 + r;
                wsum[row * 4 + wave] = p;
                wsq [row * 4 + wave] = q;
            }
        }
    }
    __syncthreads();
    if (tid < 64) {
        float s  = wsum[tid * 4] + wsum[tid * 4 + 1] + wsum[tid * 4 + 2] + wsum[tid * 4 + 3];
        float ss = wsq [tid * 4] + wsq [tid * 4 + 1] + wsq [tid * 4 + 2] + wsq [tid * 4 + 3];
        float m = s * (1.f / 192.f);
        float var = ss * (1.f / 192.f) - m * m;
        mean_s[tid] = m;
        rstd_s[tid] = rsqrtf(fmaxf(var, 0.f) + 1e-5f);
    }
    __syncthreads();

#pragma unroll
    for (int mt = 0; mt < 4; ++mt) {
#pragma unroll
        for (int r = 0; r < 4; ++r) {
            int row = mt * 16 + quad * 4 + r;
            long tok = tok0 + row;
            if (tok < 131040) {
                float m = mean_s[row], rsd = rstd_s[row];
#pragma unroll
                for (int nt = 0; nt < 3; ++nt) {
                    int c = colw + nt * 16 + l15;
                    float val = (o[nt][mt][r] - m) * rsd * gw[nt] + gb[nt]
                              + bf2f(Xs[row * 200 + c]);
                    out[tok * 192 + c] = val;
                }
            }
        }
    }
}

// ---------------------------------------------------------------------------
extern "C" void kernel_launch(void* const* d_in, const int* in_sizes, int n_in,
                              void* d_out, int out_size, void* d_ws, size_t ws_size,
                              hipStream_t stream) {
    (void)in_sizes; (void)n_in; (void)out_size; (void)ws_size;
    const float* x          = (const float*)d_in[0];
    const float* qkv_w      = (const float*)d_in[1];
    const float* qkv_b      = (const float*)d_in[2];
    const float* proj_w     = (const float*)d_in[3];
    const float* proj_b     = (const float*)d_in[4];
    const float* bias_table = (const float*)d_in[5];
    const float* n1w        = (const float*)d_in[6];
    const float* n1b        = (const float*)d_in[7];
    const float* n2w        = (const float*)d_in[8];
    const float* n2b        = (const float*)d_in[9];
    const float* w1         = (const float*)d_in[10];
    const float* b1         = (const float*)d_in[11];
    const float* w2         = (const float*)d_in[12];
    const float* b2         = (const float*)d_in[13];
    float* out = (float*)d_out;

    // ws layout:
    //  [0, 53084160)            attn rows bf16 (dead after proj; start reused for w1b/w2b)
    //  [53084160, +50319360)    x1 bf16 (written by proj). BEFORE proj runs, this
    //                           region hosts attn prep data (read only by attn):
    //    qkv_wb @53084160 (221184 B) | qkv_bb @53305344 (2304 B) | biasT @53307648 (15925248 B)
    bf16*  attn_ws = (bf16*)d_ws;
    bf16*  x1_ws   = (bf16*)((char*)d_ws + 53084160);
    bf16*  w1b     = (bf16*)d_ws;
    bf16*  w2b     = (bf16*)((char*)d_ws + 294912);
    bf16*  qkv_wb  = (bf16*)((char*)d_ws + 53084160);
    float* qkv_bb  = (float*)((char*)d_ws + 53305344);
    bf16*  biasT   = (bf16*)((char*)d_ws + 53307648);

    prep_attn_w<<<432, 256, 0, stream>>>(qkv_w, qkv_b, qkv_wb, qkv_bb);
    prep_bias<<<31104, 256, 0, stream>>>(bias_table, biasT);
    attn_mfma_kernel<<<5760, 256, 0, stream>>>(x, qkv_wb, qkv_bb, biasT, attn_ws);
    proj_mfma_kernel<<<1024, 256, 0, stream>>>(attn_ws, proj_w, proj_b, x, n1w, n1b, x1_ws);
    prep_weights<<<576, 256, 0, stream>>>(w1, w2, (unsigned int*)w1b, (unsigned int*)w2b);
    mlp_mfma_kernel<<<2048, 256, 0, stream>>>(x1_ws, w1b, b1, w2b, b2, n2w, n2b, out);
}

// Round 6
// 716.370 us; speedup vs baseline: 1.0939x; 1.0555x over previous
//
#include <hip/hip_runtime.h>
#include <hip/hip_bf16.h>

typedef __hip_bfloat16 bf16;
#define DEVI __device__ __forceinline__

typedef __bf16 bf16x8 __attribute__((ext_vector_type(8)));
typedef __bf16 bf16x4 __attribute__((ext_vector_type(4)));
typedef float  f32x4  __attribute__((ext_vector_type(4)));

DEVI float bf2f(bf16 v) { return __bfloat162float(v); }
DEVI bf16 f2bf(float v) { return __float2bfloat16(v); }
DEVI float bfu2f(unsigned short u) { return __uint_as_float((unsigned)u << 16); }

DEVI unsigned short bfbits(float x) {
    bf16 h = __float2bfloat16(x);
    return *reinterpret_cast<unsigned short*>(&h);
}
DEVI unsigned int pack2(float x, float y) {
    return (unsigned int)bfbits(x) | ((unsigned int)bfbits(y) << 16);
}
DEVI bf16x8 pack8(float4 lo, float4 hi) {
    union { unsigned int u[4]; bf16x8 v; } z;
    z.u[0] = pack2(lo.x, lo.y); z.u[1] = pack2(lo.z, lo.w);
    z.u[2] = pack2(hi.x, hi.y); z.u[3] = pack2(hi.z, hi.w);
    return z.v;
}
// LDS bf16x8 load from an 8-byte-aligned (not 16) address: two b64 halves
DEVI bf16x8 ld8h(const bf16* p) {
    bf16x4 lo = *(const bf16x4*)p;
    bf16x4 hi = *(const bf16x4*)(p + 4);
    return __builtin_shufflevector(lo, hi, 0, 1, 2, 3, 4, 5, 6, 7);
}

// ---------------------------------------------------------------------------
// Prep A: reorder qkv weights per head into [h][96][192] bf16, fold 1/sqrt(32)
// into the q rows and q bias. qkv_bb fp32 [576] in [h][96] order.
// ---------------------------------------------------------------------------
__global__ __launch_bounds__(256) void prep_attn_w(
    const float* __restrict__ qkv_w, const float* __restrict__ qkv_b,
    bf16* __restrict__ qkv_wb, float* __restrict__ qkv_bb)
{
    const float scale = 0.17677669529663687f;
    int idx = blockIdx.x * 256 + threadIdx.x;
    if (idx < 110592) {
        int c = idx % 192, d = idx / 192;
        int h = d / 96, q2 = d - h * 96, seg = q2 >> 5, rr = q2 & 31;
        float v = qkv_w[(size_t)(seg * 192 + h * 32 + rr) * 192 + c];
        if (seg == 0) v *= scale;
        qkv_wb[idx] = f2bf(v);
    }
    if (idx < 576) {
        int h = idx / 96, q2 = idx - h * 96, seg = q2 >> 5, rr = q2 & 31;
        float b = qkv_b[seg * 192 + h * 32 + rr];
        if (seg == 0) b *= scale;
        qkv_bb[idx] = b;
    }
}

// ---------------------------------------------------------------------------
// Prep B: earth bias tiles biasT[wb][h][tok][key] bf16 (query-major, so the
// attn kernels can load 4 keys per 8B vector load).
// ---------------------------------------------------------------------------
__global__ __launch_bounds__(256) void prep_bias(
    const float* __restrict__ bias_table, bf16* __restrict__ biasT)
{
    int idx = blockIdx.x * 256 + threadIdx.x;
    if (idx >= 7962624) return;
    int m = idx % 144;             // key
    int n = (idx / 144) % 144;     // tok (query)
    int r2 = idx / 20736;
    int h = r2 % 6, wb = r2 / 6;
    int tzn = n / 72, thn = (n / 12) % 6, twn = n % 12;
    int tzm = m / 72, thm = (m / 12) % 6, twm = m % 12;
    int bidx = (tzn + 2 * tzm) * 828 + (thn + 6 * thm) * 23 + (twn - twm + 11);
    biasT[idx] = f2bf(bias_table[(size_t)(bidx * 64 + wb) * 6 + h]);
}

// ---------------------------------------------------------------------------
// zero the VT pad columns [144,160) of every [32][160] row (split path only)
// ---------------------------------------------------------------------------
__global__ __launch_bounds__(256) void zero_vtpad(bf16* __restrict__ vt)
{
    int idx = blockIdx.x * 256 + threadIdx.x;   // 368640 = 184320 rows x 2
    if (idx >= 368640) return;
    int row = idx >> 1, half = idx & 1;
    uint4 z = make_uint4(0u, 0u, 0u, 0u);
    *(uint4*)(vt + (size_t)row * 160 + 144 + half * 8) = z;
}

// ---------------------------------------------------------------------------
// QKV dense GEMM (split path): 48-token M-block per window third, 4 waves x
// 144 cols, K=192.  Writes per head:
//   qk[((wi*6+h)*2+seg)][tok][32]  (seg 0=Q scaled, 1=K)
//   vt[(wi*6+h)][d(32)][160]       (V transposed, pad cols zeroed separately)
// ---------------------------------------------------------------------------
__global__ __launch_bounds__(256, 2) void qkv_gemm_kernel(
    const float* __restrict__ x, const bf16* __restrict__ qkv_wb,
    const float* __restrict__ qkv_bb, bf16* __restrict__ qk,
    bf16* __restrict__ vt)
{
    __shared__ alignas(16) bf16 Xs[48 * 200];
    const int tid  = threadIdx.x;
    const int wave = tid >> 6;
    const int lane = tid & 63;
    const int quad = lane >> 4;
    const int l15  = lane & 15;
    const int b    = blockIdx.x;
    const int wi   = b / 3, tblk = b % 3;
    const int ww_  = wi % 15;
    const int hw   = (wi / 15) % 16;
    const int zw   = wi / 240;

    // gather x window rows [tblk*48, +48) with lat mapping (fp32 -> bf16)
    for (int i = tid; i < 48 * 24; i += 256) {
        int r = i / 24, c8 = i - r * 24;
        int t  = tblk * 48 + r;
        int tz = t / 72, rr = t - tz * 72;
        int th = rr / 12, tw = rr - th * 12;
        int lat = hw * 6 + th - 2;
        bool valid = (lat >= 0 && lat < 91);
        uint4 val = make_uint4(0u, 0u, 0u, 0u);
        if (valid) {
            size_t base = ((size_t)((zw * 2 + tz) * 91 + lat) * 180
                           + ww_ * 12 + tw) * 192;
            float4 lo = *(const float4*)(x + base + c8 * 8);
            float4 hi = *(const float4*)(x + base + c8 * 8 + 4);
            bf16x8 p = pack8(lo, hi);
            val = *(uint4*)&p;
        }
        *(uint4*)(Xs + r * 200 + c8 * 8) = val;
    }
    __syncthreads();

    bf16x8 af[3][6];
#pragma unroll
    for (int mt = 0; mt < 3; ++mt)
#pragma unroll
        for (int ks = 0; ks < 6; ++ks)
            af[mt][ks] = *(const bf16x8*)(Xs + (mt * 16 + l15) * 200 + ks * 32 + quad * 8);

    const int colw = wave * 144;
    for (int nt = 0; nt < 9; ++nt) {
        int c0  = colw + nt * 16;          // 16-col tile, head/seg uniform
        int h   = c0 / 96, q20 = c0 % 96;
        int seg = q20 >> 5, rr0 = q20 & 31;
        const bf16* wrow = qkv_wb + (size_t)(h * 96 + q20 + l15) * 192;
        bf16x8 wfr[6];
#pragma unroll
        for (int ks = 0; ks < 6; ++ks)
            wfr[ks] = *(const bf16x8*)(wrow + ks * 32 + quad * 8);
        float bias = qkv_bb[h * 96 + q20 + l15];

        f32x4 acc[3];
#pragma unroll
        for (int mt = 0; mt < 3; ++mt) acc[mt] = (f32x4){0.f, 0.f, 0.f, 0.f};
#pragma unroll
        for (int ks = 0; ks < 6; ++ks)
#pragma unroll
            for (int mt = 0; mt < 3; ++mt)
                acc[mt] = __builtin_amdgcn_mfma_f32_16x16x32_bf16(
                    af[mt][ks], wfr[ks], acc[mt], 0, 0, 0);

        if (seg < 2) {
            bf16* dst = qk + (size_t)((wi * 6 + h) * 2 + seg) * 4608 + rr0 + l15;
#pragma unroll
            for (int mt = 0; mt < 3; ++mt)
#pragma unroll
                for (int r = 0; r < 4; ++r) {
                    int tok = tblk * 48 + mt * 16 + quad * 4 + r;
                    dst[tok * 32] = f2bf(acc[mt][r] + bias);
                }
        } else {
            bf16* dst = vt + ((size_t)(wi * 6 + h) * 32 + rr0 + l15) * 160;
#pragma unroll
            for (int mt = 0; mt < 3; ++mt)
#pragma unroll
                for (int r = 0; r < 4; ++r) {
                    int tok = tblk * 48 + mt * 16 + quad * 4 + r;
                    dst[tok] = f2bf(acc[mt][r] + bias);
                }
        }
    }
}

// ---------------------------------------------------------------------------
// Slim attention (split path): one block per (window, head), 4 waves, NO LDS,
// NO barriers. Q/K/V read straight from global (L1/L2-hot block slices).
// Swapped S^T = K·Q^T, in-register softmax, shfl-built PV A-fragments.
// ---------------------------------------------------------------------------
__global__ __launch_bounds__(256, 4) void attn_slim_kernel(
    const bf16* __restrict__ qk, const bf16* __restrict__ vt,
    const bf16* __restrict__ biasT, bf16* __restrict__ attn_out)
{
    const int tid  = threadIdx.x;
    const int wave = tid >> 6;
    const int lane = tid & 63;
    const int quad = lane >> 4;
    const int l15  = lane & 15;

    // XCD-chunked swizzle: 5760 = 8 XCDs x 720, head-fastest logical order
    const int bid     = blockIdx.x;
    const int logical = (bid & 7) * 720 + (bid >> 3);
    const int wi      = logical / 6;
    const int head    = logical % 6;
    const int hw = (wi / 15) % 16;
    const int zw = wi / 240;
    const int wb = zw * 16 + hw;

    const bf16* Qg = qk + (size_t)((wi * 6 + head) * 2) * 4608;
    const bf16* Kg = Qg + 4608;
    const bf16* Vg = vt + (size_t)(wi * 6 + head) * 32 * 160;
    const bf16* bt = biasT + (size_t)(wb * 6 + head) * 20736;

    for (int i = 0; i < 3; ++i) {
        int nti = wave + 4 * i;
        if (nti >= 9) continue;   // no barriers: waves fully independent

        bf16x8 qb = *(const bf16x8*)(Qg + (nti * 16 + l15) * 32 + quad * 8);

        // S^T: st[mt] = S[tok=16*nti+l15][key=16*mt+quad*4+r]
        f32x4 st[9];
#pragma unroll
        for (int mt = 0; mt < 9; ++mt) {
            bf16x8 ka = *(const bf16x8*)(Kg + (mt * 16 + l15) * 32 + quad * 8);
            st[mt] = (f32x4){0.f, 0.f, 0.f, 0.f};
            st[mt] = __builtin_amdgcn_mfma_f32_16x16x32_bf16(
                ka, qb, st[mt], 0, 0, 0);
        }

        // + earth bias: [tok][key] layout -> 8B vector per mt
        const bf16* brow = bt + (size_t)(nti * 16 + l15) * 144 + quad * 4;
#pragma unroll
        for (int mt = 0; mt < 9; ++mt) {
            union { bf16x4 v; unsigned short u[4]; } bb_;
            bb_.v = *(const bf16x4*)(brow + mt * 16);
#pragma unroll
            for (int r = 0; r < 4; ++r)
                st[mt][r] += bfu2f(bb_.u[r]);
        }

        // softmax across 36 in-lane + 4 quads (2 shfl)
        float mx = -1e30f;
#pragma unroll
        for (int mt = 0; mt < 9; ++mt)
#pragma unroll
            for (int r = 0; r < 4; ++r) mx = fmaxf(mx, st[mt][r]);
        mx = fmaxf(mx, __shfl_xor(mx, 16, 64));
        mx = fmaxf(mx, __shfl_xor(mx, 32, 64));
        float s = 0.f;
#pragma unroll
        for (int mt = 0; mt < 9; ++mt)
#pragma unroll
            for (int r = 0; r < 4; ++r) {
                float e = __expf(st[mt][r] - mx);
                st[mt][r] = e;
                s += e;
            }
        s += __shfl_xor(s, 16, 64);
        s += __shfl_xor(s, 32, 64);
        float inv = 1.f / s;
#pragma unroll
        for (int mt = 0; mt < 9; ++mt)
#pragma unroll
            for (int r = 0; r < 4; ++r) st[mt][r] *= inv;

        // O = P V : A-frag built in-register via cross-quad exchange
        f32x4 oa[2];
        oa[0] = (f32x4){0.f, 0.f, 0.f, 0.f};
        oa[1] = (f32x4){0.f, 0.f, 0.f, 0.f};
#pragma unroll
        for (int ks = 0; ks < 5; ++ks) {
            unsigned A0 = pack2(st[2 * ks][0], st[2 * ks][1]);
            unsigned A1 = pack2(st[2 * ks][2], st[2 * ks][3]);
            unsigned B0 = 0u, B1 = 0u;
            if (ks < 4) {
                B0 = pack2(st[2 * ks + 1][0], st[2 * ks + 1][1]);
                B1 = pack2(st[2 * ks + 1][2], st[2 * ks + 1][3]);
            }
            bool lo2 = quad < 2;
            unsigned Z0 = lo2 ? A0 : B0, Z1 = lo2 ? A1 : B1;
            unsigned Y0 = lo2 ? B0 : A0, Y1 = lo2 ? B1 : A1;
            unsigned s16_0 = __shfl_xor((int)Z0, 16, 64);
            unsigned s16_1 = __shfl_xor((int)Z1, 16, 64);
            unsigned s32_0 = __shfl_xor((int)Y0, 32, 64);
            unsigned s32_1 = __shfl_xor((int)Y1, 32, 64);
            unsigned s48_0 = __shfl_xor((int)Y0, 48, 64);
            unsigned s48_1 = __shfl_xor((int)Y1, 48, 64);
            union { unsigned u[4]; bf16x8 v; } fr;
            fr.u[0] = (quad == 0) ? Z0 : (quad == 1) ? s48_0 : (quad == 2) ? s32_0 : s16_0;
            fr.u[1] = (quad == 0) ? Z1 : (quad == 1) ? s48_1 : (quad == 2) ? s32_1 : s16_1;
            fr.u[2] = (quad == 0) ? s16_0 : (quad == 1) ? s32_0 : (quad == 2) ? s48_0 : Z0;
            fr.u[3] = (quad == 0) ? s16_1 : (quad == 1) ? s32_1 : (quad == 2) ? s48_1 : Z1;
#pragma unroll
            for (int n2 = 0; n2 < 2; ++n2) {
                bf16x8 vb = *(const bf16x8*)(Vg + (n2 * 16 + l15) * 160
                                             + ks * 32 + quad * 8);
                oa[n2] = __builtin_amdgcn_mfma_f32_16x16x32_bf16(
                    fr.v, vb, oa[n2], 0, 0, 0);
            }
        }

#pragma unroll
        for (int n2 = 0; n2 < 2; ++n2)
#pragma unroll
            for (int r = 0; r < 4; ++r) {
                int tok = nti * 16 + quad * 4 + r;
                attn_out[(size_t)(wi * 144 + tok) * 192 + (head << 5) + n2 * 16 + l15]
                    = f2bf(oa[n2][r]);
            }
    }
}

// ---------------------------------------------------------------------------
// Fused attention (fallback path, R4 structure; bias load vectorized)
// ---------------------------------------------------------------------------
__global__ __launch_bounds__(256, 4) void attn_fused_kernel(
    const float* __restrict__ x, const bf16* __restrict__ qkv_wb,
    const float* __restrict__ qkv_bb, const bf16* __restrict__ biasT,
    bf16* __restrict__ attn_out)
{
    __shared__ alignas(16) char sm[30976];
    bf16* Qs  = (bf16*)sm;
    bf16* Ks  = (bf16*)(sm + 10368);
    bf16* VTs = (bf16*)(sm + 20736);

    const int tid  = threadIdx.x;
    const int wave = tid >> 6;
    const int lane = tid & 63;
    const int quad = lane >> 4;
    const int l15  = lane & 15;

    const int bid     = blockIdx.x;
    const int logical = (bid & 7) * 720 + (bid >> 3);
    const int wi      = logical / 6;
    const int head    = logical % 6;
    const int ww_  = wi % 15;
    const int hw   = (wi / 15) % 16;
    const int zw   = wi / 240;
    const int wb   = zw * 16 + hw;

    for (int i = tid; i < 512; i += 256) {
        int d = i >> 4, c = i & 15;
        VTs[d * 160 + 144 + c] = f2bf(0.f);
    }

    for (int i = 0; i < 3; ++i) {
        int mt = wave + 4 * i;
        if (mt < 9) {
            int t  = mt * 16 + l15;
            int tz = t / 72, rr = t - tz * 72;
            int th = rr / 12, tw = rr - th * 12;
            int lat = hw * 6 + th - 2;
            bool valid = (lat >= 0 && lat < 91);
            size_t base = ((size_t)((zw * 2 + tz) * 91 + (valid ? lat : 0)) * 180
                           + ww_ * 12 + tw) * 192;
            bf16x8 af[6];
#pragma unroll
            for (int ks = 0; ks < 6; ++ks) {
                float4 lo = make_float4(0.f, 0.f, 0.f, 0.f);
                float4 hi = make_float4(0.f, 0.f, 0.f, 0.f);
                if (valid) {
                    lo = *(const float4*)(x + base + ks * 32 + quad * 8);
                    hi = *(const float4*)(x + base + ks * 32 + quad * 8 + 4);
                }
                af[ks] = pack8(lo, hi);
            }
            for (int nt = 0; nt < 6; ++nt) {
                const bf16* wrow = qkv_wb + (size_t)(head * 96 + nt * 16 + l15) * 192;
                bf16x8 bw[6];
#pragma unroll
                for (int ks = 0; ks < 6; ++ks)
                    bw[ks] = *(const bf16x8*)(wrow + ks * 32 + quad * 8);
                float bias = qkv_bb[head * 96 + nt * 16 + l15];

                f32x4 acc = (f32x4){0.f, 0.f, 0.f, 0.f};
#pragma unroll
                for (int ks = 0; ks < 6; ++ks)
                    acc = __builtin_amdgcn_mfma_f32_16x16x32_bf16(
                        af[ks], bw[ks], acc, 0, 0, 0);
#pragma unroll
                for (int r = 0; r < 4; ++r) {
                    float v = acc[r] + bias;
                    int tok = mt * 16 + quad * 4 + r;
                    if (nt < 2)      Qs[tok * 36 + nt * 16 + l15] = f2bf(v);
                    else if (nt < 4) Ks[tok * 36 + (nt - 2) * 16 + l15] = f2bf(v);
                    else             VTs[((nt - 4) * 16 + l15) * 160 + tok] = f2bf(v);
                }
            }
        }
    }
    __syncthreads();

    const bf16* bt = biasT + (size_t)(wb * 6 + head) * 20736;

    for (int i = 0; i < 3; ++i) {
        int nti = wave + 4 * i;
        if (nti >= 9) continue;

        bf16x8 qb = ld8h(Qs + (nti * 16 + l15) * 36 + quad * 8);

        f32x4 st[9];
#pragma unroll
        for (int mt = 0; mt < 9; ++mt) {
            bf16x8 ka = ld8h(Ks + (mt * 16 + l15) * 36 + quad * 8);
            st[mt] = (f32x4){0.f, 0.f, 0.f, 0.f};
            st[mt] = __builtin_amdgcn_mfma_f32_16x16x32_bf16(
                ka, qb, st[mt], 0, 0, 0);
        }

        const bf16* brow = bt + (size_t)(nti * 16 + l15) * 144 + quad * 4;
#pragma unroll
        for (int mt = 0; mt < 9; ++mt) {
            union { bf16x4 v; unsigned short u[4]; } bb_;
            bb_.v = *(const bf16x4*)(brow + mt * 16);
#pragma unroll
            for (int r = 0; r < 4; ++r)
                st[mt][r] += bfu2f(bb_.u[r]);
        }

        float mx = -1e30f;
#pragma unroll
        for (int mt = 0; mt < 9; ++mt)
#pragma unroll
            for (int r = 0; r < 4; ++r) mx = fmaxf(mx, st[mt][r]);
        mx = fmaxf(mx, __shfl_xor(mx, 16, 64));
        mx = fmaxf(mx, __shfl_xor(mx, 32, 64));
        float s = 0.f;
#pragma unroll
        for (int mt = 0; mt < 9; ++mt)
#pragma unroll
            for (int r = 0; r < 4; ++r) {
                float e = __expf(st[mt][r] - mx);
                st[mt][r] = e;
                s += e;
            }
        s += __shfl_xor(s, 16, 64);
        s += __shfl_xor(s, 32, 64);
        float inv = 1.f / s;
#pragma unroll
        for (int mt = 0; mt < 9; ++mt)
#pragma unroll
            for (int r = 0; r < 4; ++r) st[mt][r] *= inv;

        f32x4 oa[2];
        oa[0] = (f32x4){0.f, 0.f, 0.f, 0.f};
        oa[1] = (f32x4){0.f, 0.f, 0.f, 0.f};
#pragma unroll
        for (int ks = 0; ks < 5; ++ks) {
            unsigned A0 = pack2(st[2 * ks][0], st[2 * ks][1]);
            unsigned A1 = pack2(st[2 * ks][2], st[2 * ks][3]);
            unsigned B0 = 0u, B1 = 0u;
            if (ks < 4) {
                B0 = pack2(st[2 * ks + 1][0], st[2 * ks + 1][1]);
                B1 = pack2(st[2 * ks + 1][2], st[2 * ks + 1][3]);
            }
            bool lo2 = quad < 2;
            unsigned Z0 = lo2 ? A0 : B0, Z1 = lo2 ? A1 : B1;
            unsigned Y0 = lo2 ? B0 : A0, Y1 = lo2 ? B1 : A1;
            unsigned s16_0 = __shfl_xor((int)Z0, 16, 64);
            unsigned s16_1 = __shfl_xor((int)Z1, 16, 64);
            unsigned s32_0 = __shfl_xor((int)Y0, 32, 64);
            unsigned s32_1 = __shfl_xor((int)Y1, 32, 64);
            unsigned s48_0 = __shfl_xor((int)Y0, 48, 64);
            unsigned s48_1 = __shfl_xor((int)Y1, 48, 64);
            union { unsigned u[4]; bf16x8 v; } fr;
            fr.u[0] = (quad == 0) ? Z0 : (quad == 1) ? s48_0 : (quad == 2) ? s32_0 : s16_0;
            fr.u[1] = (quad == 0) ? Z1 : (quad == 1) ? s48_1 : (quad == 2) ? s32_1 : s16_1;
            fr.u[2] = (quad == 0) ? s16_0 : (quad == 1) ? s32_0 : (quad == 2) ? s48_0 : Z0;
            fr.u[3] = (quad == 0) ? s16_1 : (quad == 1) ? s32_1 : (quad == 2) ? s48_1 : Z1;
#pragma unroll
            for (int n2 = 0; n2 < 2; ++n2) {
                bf16x8 vb = *(const bf16x8*)(VTs + (n2 * 16 + l15) * 160
                                             + ks * 32 + quad * 8);
                oa[n2] = __builtin_amdgcn_mfma_f32_16x16x32_bf16(
                    fr.v, vb, oa[n2], 0, 0, 0);
            }
        }

#pragma unroll
        for (int n2 = 0; n2 < 2; ++n2)
#pragma unroll
            for (int r = 0; r < 4; ++r) {
                int tok = nti * 16 + quad * 4 + r;
                attn_out[(size_t)(wi * 144 + tok) * 192 + (head << 5) + n2 * 16 + l15]
                    = f2bf(oa[n2][r]);
            }
    }
}

// ---------------------------------------------------------------------------
// Kernel 2 (MFMA): proj + window-reverse/crop + LN1 + residual -> x1
// ---------------------------------------------------------------------------
__global__ __launch_bounds__(256, 2) void proj_mfma_kernel(
    const bf16* __restrict__ attn, const float* __restrict__ proj_w,
    const float* __restrict__ proj_b, const float* __restrict__ xin,
    const float* __restrict__ n1w, const float* __restrict__ n1b,
    bf16* __restrict__ x1out)
{
    __shared__ alignas(16) char sm[56320];
    bf16*  Xs     = (bf16*)sm;
    float* wsum   = (float*)(sm + 51200);
    float* wsq    = (float*)(sm + 53248);
    float* mean_s = (float*)(sm + 55296);
    float* rstd_s = (float*)(sm + 55808);

    const int tid  = threadIdx.x;
    const int wave = tid >> 6;
    const int lane = tid & 63;
    const int quad = lane >> 4;
    const int l15  = lane & 15;
    const long tok0 = (long)blockIdx.x * 128;
    const int colw = wave * 48;

    for (int i = tid; i < 128 * 24; i += 256) {
        int r = i / 24, c4 = i - r * 24;
        long l = tok0 + r;
        uint4 v = make_uint4(0u, 0u, 0u, 0u);
        if (l < 131040) {
            int li  = (int)l;
            int z   = li / 16380, rem = li - z * 16380;
            int lat = rem / 180, lon = rem - lat * 180;
            int latp = lat + 2;
            int zw = z >> 1, tz = z & 1;
            int hw = latp / 6, th = latp - hw * 6;
            int wwn = lon / 12, tw = lon - wwn * 12;
            int wi = (zw * 16 + hw) * 15 + wwn;
            int t  = (tz * 6 + th) * 12 + tw;
            v = *(const uint4*)(attn + (size_t)(wi * 144 + t) * 192 + c4 * 8);
        }
        *(uint4*)(Xs + r * 200 + c4 * 8) = v;
    }
    __syncthreads();

    f32x4 o[3][8];
#pragma unroll
    for (int nt = 0; nt < 3; ++nt)
#pragma unroll
        for (int mt = 0; mt < 8; ++mt)
            o[nt][mt] = (f32x4){0.f, 0.f, 0.f, 0.f};

#pragma unroll
    for (int ks = 0; ks < 6; ++ks) {
        bf16x8 wfr[3];
#pragma unroll
        for (int nt = 0; nt < 3; ++nt) {
            const float* wp = proj_w + (size_t)(colw + nt * 16 + l15) * 192
                            + ks * 32 + quad * 8;
            float4 lo = *(const float4*)wp;
            float4 hi = *(const float4*)(wp + 4);
            wfr[nt] = pack8(lo, hi);
        }
#pragma unroll
        for (int mt = 0; mt < 8; ++mt) {
            bf16x8 a = *(const bf16x8*)(Xs + (mt * 16 + l15) * 200 + ks * 32 + quad * 8);
#pragma unroll
            for (int nt = 0; nt < 3; ++nt)
                o[nt][mt] = __builtin_amdgcn_mfma_f32_16x16x32_bf16(
                    a, wfr[nt], o[nt][mt], 0, 0, 0);
        }
    }

    float pbv[3], gw[3], gb[3];
#pragma unroll
    for (int nt = 0; nt < 3; ++nt) {
        int c = colw + nt * 16 + l15;
        pbv[nt] = proj_b[c];
        gw[nt]  = n1w[c];
        gb[nt]  = n1b[c];
    }
#pragma unroll
    for (int nt = 0; nt < 3; ++nt)
#pragma unroll
        for (int mt = 0; mt < 8; ++mt)
#pragma unroll
            for (int r = 0; r < 4; ++r)
                o[nt][mt][r] += pbv[nt];

#pragma unroll
    for (int mt = 0; mt < 8; ++mt) {
#pragma unroll
        for (int r = 0; r < 4; ++r) {
            float p = o[0][mt][r] + o[1][mt][r] + o[2][mt][r];
            float q = o[0][mt][r] * o[0][mt][r] + o[1][mt][r] * o[1][mt][r]
                    + o[2][mt][r] * o[2][mt][r];
#pragma unroll
            for (int m_ = 1; m_ < 16; m_ <<= 1) {
                p += __shfl_xor(p, m_, 64);
                q += __shfl_xor(q, m_, 64);
            }
            if (l15 == 0) {
                int row = mt * 16 + quad * 4 + r;
                wsum[row * 4 + wave] = p;
                wsq [row * 4 + wave] = q;
            }
        }
    }
    __syncthreads();
    if (tid < 128) {
        float s  = wsum[tid * 4] + wsum[tid * 4 + 1] + wsum[tid * 4 + 2] + wsum[tid * 4 + 3];
        float ss = wsq [tid * 4] + wsq [tid * 4 + 1] + wsq [tid * 4 + 2] + wsq [tid * 4 + 3];
        float m = s * (1.f / 192.f);
        float var = ss * (1.f / 192.f) - m * m;
        mean_s[tid] = m;
        rstd_s[tid] = rsqrtf(fmaxf(var, 0.f) + 1e-5f);
    }
    __syncthreads();

#pragma unroll
    for (int mt = 0; mt < 8; ++mt) {
#pragma unroll
        for (int r = 0; r < 4; ++r) {
            int row = mt * 16 + quad * 4 + r;
            long tok = tok0 + row;
            if (tok < 131040) {
                float m = mean_s[row], rsd = rstd_s[row];
#pragma unroll
                for (int nt = 0; nt < 3; ++nt) {
                    int c = colw + nt * 16 + l15;
                    float val = (o[nt][mt][r] - m) * rsd * gw[nt] + gb[nt]
                              + xin[(size_t)tok * 192 + c];
                    x1out[(size_t)tok * 192 + c] = f2bf(val);
                }
            }
        }
    }
}

// ---------------------------------------------------------------------------
// Prep C: convert w1/w2 fp32 -> bf16
// ---------------------------------------------------------------------------
__global__ __launch_bounds__(256) void prep_weights(
    const float* __restrict__ w1, const float* __restrict__ w2,
    unsigned int* __restrict__ w1b, unsigned int* __restrict__ w2b)
{
    int i = blockIdx.x * 256 + threadIdx.x;
    if (i < 73728) {
        w1b[i] = pack2(w1[2 * i], w1[2 * i + 1]);
    } else {
        int j = i - 73728;
        w2b[j] = pack2(w2[2 * j], w2[2 * j + 1]);
    }
}

// ---------------------------------------------------------------------------
// Kernel 3 (MFMA): fused MLP + LN2 + residual
// ---------------------------------------------------------------------------
__global__ __launch_bounds__(256, 2) void mlp_mfma_kernel(
    const bf16* __restrict__ x1, const bf16* __restrict__ w1b,
    const float* __restrict__ b1, const bf16* __restrict__ w2b,
    const float* __restrict__ b2, const float* __restrict__ n2w,
    const float* __restrict__ n2b, float* __restrict__ out)
{
    __shared__ alignas(16) char sm[53760];
    bf16*  Xs     = (bf16*)sm;
    bf16*  Hs     = (bf16*)(sm + 25600);
    float* wsum   = (float*)(sm + 51200);
    float* wsq    = (float*)(sm + 52224);
    float* mean_s = (float*)(sm + 53248);
    float* rstd_s = (float*)(sm + 53504);

    const int tid  = threadIdx.x;
    const int wave = tid >> 6;
    const int lane = tid & 63;
    const int quad = lane >> 4;
    const int l15  = lane & 15;
    const long tok0 = (long)blockIdx.x * 64;
    const int colw = wave * 48;

    for (int i = tid; i < 64 * 24; i += 256) {
        int r = i / 24, c8 = i - r * 24;
        uint4 v = make_uint4(0u, 0u, 0u, 0u);
        if (tok0 + r < 131040)
            v = *(const uint4*)(x1 + (tok0 + r) * 192 + (size_t)c8 * 8);
        *(uint4*)(Xs + r * 200 + c8 * 8) = v;
    }
    __syncthreads();

    bf16x8 af[4][6];
#pragma unroll
    for (int mt = 0; mt < 4; ++mt)
#pragma unroll
        for (int ks = 0; ks < 6; ++ks)
            af[mt][ks] = *(const bf16x8*)(Xs + (mt * 16 + l15) * 200 + ks * 32 + quad * 8);

    f32x4 o[3][4];
#pragma unroll
    for (int nt = 0; nt < 3; ++nt)
#pragma unroll
        for (int mt = 0; mt < 4; ++mt)
            o[nt][mt] = (f32x4){0.f, 0.f, 0.f, 0.f};

    for (int nc = 0; nc < 4; ++nc) {
        f32x4 g[3][4];
#pragma unroll
        for (int nt = 0; nt < 3; ++nt)
#pragma unroll
            for (int mt = 0; mt < 4; ++mt)
                g[nt][mt] = (f32x4){0.f, 0.f, 0.f, 0.f};
        const int h0 = nc * 192 + colw;
#pragma unroll
        for (int ks = 0; ks < 6; ++ks) {
            bf16x8 bfr[3];
#pragma unroll
            for (int nt = 0; nt < 3; ++nt)
                bfr[nt] = *(const bf16x8*)(w1b + (size_t)(h0 + nt * 16 + l15) * 192 + ks * 32 + quad * 8);
#pragma unroll
            for (int nt = 0; nt < 3; ++nt)
#pragma unroll
                for (int mt = 0; mt < 4; ++mt)
                    g[nt][mt] = __builtin_amdgcn_mfma_f32_16x16x32_bf16(
                        af[mt][ks], bfr[nt], g[nt][mt], 0, 0, 0);
        }
        __syncthreads();

#pragma unroll
        for (int nt = 0; nt < 3; ++nt) {
            float bb = b1[h0 + nt * 16 + l15];
            int hcol = colw + nt * 16 + l15;
#pragma unroll
            for (int mt = 0; mt < 4; ++mt) {
#pragma unroll
                for (int r = 0; r < 4; ++r) {
                    float v = g[nt][mt][r] + bb;
                    float u = v * (0.7978845608028654f + 0.035677408136300125f * v * v);
                    float e = __expf(2.f * u);
                    float t = 1.f - 2.f / (e + 1.f);
                    float gl = 0.5f * v * (1.f + t);
                    Hs[(mt * 16 + quad * 4 + r) * 200 + hcol] = f2bf(gl);
                }
            }
        }
        __syncthreads();

#pragma unroll
        for (int ks = 0; ks < 6; ++ks) {
            bf16x8 hf[4];
#pragma unroll
            for (int mt = 0; mt < 4; ++mt)
                hf[mt] = *(const bf16x8*)(Hs + (mt * 16 + l15) * 200 + ks * 32 + quad * 8);
            bf16x8 wf[3];
#pragma unroll
            for (int nt = 0; nt < 3; ++nt)
                wf[nt] = *(const bf16x8*)(w2b + (size_t)(colw + nt * 16 + l15) * 768 + nc * 192 + ks * 32 + quad * 8);
#pragma unroll
            for (int nt = 0; nt < 3; ++nt)
#pragma unroll
                for (int mt = 0; mt < 4; ++mt)
                    o[nt][mt] = __builtin_amdgcn_mfma_f32_16x16x32_bf16(
                        hf[mt], wf[nt], o[nt][mt], 0, 0, 0);
        }
    }

    float b2v[3], gw[3], gb[3];
#pragma unroll
    for (int nt = 0; nt < 3; ++nt) {
        int c = colw + nt * 16 + l15;
        b2v[nt] = b2[c];
        gw[nt] = n2w[c];
        gb[nt] = n2b[c];
    }
#pragma unroll
    for (int nt = 0; nt < 3; ++nt)
#pragma unroll
        for (int mt = 0; mt < 4; ++mt)
#pragma unroll
            for (int r = 0; r < 4; ++r)
                o[nt][mt][r] += b2v[nt];

#pragma unroll
    for (int mt = 0; mt < 4; ++mt) {
#pragma unroll
        for (int r = 0; r < 4; ++r) {
            float p = o[0][mt][r] + o[1][mt][r] + o[2][mt][r];
            float q = o[0][mt][r] * o[0][mt][r] + o[1][mt][r] * o[1][mt][r]
                    + o[2][mt][r] * o[2][mt][r];
#pragma unroll
            for (int m_ = 1; m_ < 16; m_ <<= 1) {
                p += __shfl_xor(p, m_, 64);
                q += __shfl_xor(q, m_, 64);
            }
            if (l15 == 0) {
                int row = mt * 16 + quad * 4 + r;
                wsum[row * 4 + wave] = p;
                wsq [row * 4 + wave] = q;
            }
        }
    }
    __syncthreads();
    if (tid < 64) {
        float s  = wsum[tid * 4] + wsum[tid * 4 + 1] + wsum[tid * 4 + 2] + wsum[tid * 4 + 3];
        float ss = wsq [tid * 4] + wsq [tid * 4 + 1] + wsq [tid * 4 + 2] + wsq [tid * 4 + 3];
        float m = s * (1.f / 192.f);
        float var = ss * (1.f / 192.f) - m * m;
        mean_s[tid] = m;
        rstd_s[tid] = rsqrtf(fmaxf(var, 0.f) + 1e-5f);
    }
    __syncthreads();

#pragma unroll
    for (int mt = 0; mt < 4; ++mt) {
#pragma unroll
        for (int r = 0; r < 4; ++r) {
            int row = mt * 16 + quad * 4 + r;
            long tok = tok0 + row;
            if (tok < 131040) {
                float m = mean_s[row], rsd = rstd_s[row];
#pragma unroll
                for (int nt = 0; nt < 3; ++nt) {
                    int c = colw + nt * 16 + l15;
                    float val = (o[nt][mt][r] - m) * rsd * gw[nt] + gb[nt]
                              + bf2f(Xs[row * 200 + c]);
                    out[tok * 192 + c] = val;
                }
            }
        }
    }
}

// ---------------------------------------------------------------------------
extern "C" void kernel_launch(void* const* d_in, const int* in_sizes, int n_in,
                              void* d_out, int out_size, void* d_ws, size_t ws_size,
                              hipStream_t stream) {
    (void)in_sizes; (void)n_in; (void)out_size;
    const float* x          = (const float*)d_in[0];
    const float* qkv_w      = (const float*)d_in[1];
    const float* qkv_b      = (const float*)d_in[2];
    const float* proj_w     = (const float*)d_in[3];
    const float* proj_b     = (const float*)d_in[4];
    const float* bias_table = (const float*)d_in[5];
    const float* n1w        = (const float*)d_in[6];
    const float* n1b        = (const float*)d_in[7];
    const float* n2w        = (const float*)d_in[8];
    const float* n2b        = (const float*)d_in[9];
    const float* w1         = (const float*)d_in[10];
    const float* b1         = (const float*)d_in[11];
    const float* w2         = (const float*)d_in[12];
    const float* b2         = (const float*)d_in[13];
    float* out = (float*)d_out;

    const size_t SPLIT_WS = 234383616ULL;
    if (ws_size >= SPLIT_WS) {
        // Split path layout:
        //  [0, 53084160)              attn rows bf16 (attn -> proj)
        //  [53084160, 159252480)      QKg bf16 (qkv -> attn); after attn dead:
        //        x1 @53084160 (50319360) | w1b @103403520 | w2b @103698432
        //  [159252480, 218234880)     VTg bf16 (qkv -> attn)
        //  [218234880, 234160128)     biasT bf16
        //  [234160128, ...)           qkv_wb | qkv_bb
        bf16*  attn_ws = (bf16*)d_ws;
        bf16*  qkg     = (bf16*)((char*)d_ws + 53084160);
        bf16*  vtg     = (bf16*)((char*)d_ws + 159252480);
        bf16*  biasT   = (bf16*)((char*)d_ws + 218234880);
        bf16*  qkv_wb  = (bf16*)((char*)d_ws + 234160128);
        float* qkv_bb  = (float*)((char*)d_ws + 234381312);
        bf16*  x1_ws   = (bf16*)((char*)d_ws + 53084160);
        bf16*  w1b     = (bf16*)((char*)d_ws + 103403520);
        bf16*  w2b     = (bf16*)((char*)d_ws + 103698432);

        prep_attn_w<<<432, 256, 0, stream>>>(qkv_w, qkv_b, qkv_wb, qkv_bb);
        prep_bias<<<31104, 256, 0, stream>>>(bias_table, biasT);
        zero_vtpad<<<1440, 256, 0, stream>>>(vtg);
        qkv_gemm_kernel<<<2880, 256, 0, stream>>>(x, qkv_wb, qkv_bb, qkg, vtg);
        attn_slim_kernel<<<5760, 256, 0, stream>>>(qkg, vtg, biasT, attn_ws);
        proj_mfma_kernel<<<1024, 256, 0, stream>>>(attn_ws, proj_w, proj_b, x, n1w, n1b, x1_ws);
        prep_weights<<<576, 256, 0, stream>>>(w1, w2, (unsigned int*)w1b, (unsigned int*)w2b);
        mlp_mfma_kernel<<<2048, 256, 0, stream>>>(x1_ws, w1b, b1, w2b, b2, n2w, n2b, out);
    } else {
        // Fallback (R4 fused) layout
        bf16*  attn_ws = (bf16*)d_ws;
        bf16*  x1_ws   = (bf16*)((char*)d_ws + 53084160);
        bf16*  w1b     = (bf16*)d_ws;
        bf16*  w2b     = (bf16*)((char*)d_ws + 294912);
        bf16*  qkv_wb  = (bf16*)((char*)d_ws + 53084160);
        float* qkv_bb  = (float*)((char*)d_ws + 53305344);
        bf16*  biasT   = (bf16*)((char*)d_ws + 53307648);

        prep_attn_w<<<432, 256, 0, stream>>>(qkv_w, qkv_b, qkv_wb, qkv_bb);
        prep_bias<<<31104, 256, 0, stream>>>(bias_table, biasT);
        attn_fused_kernel<<<5760, 256, 0, stream>>>(x, qkv_wb, qkv_bb, biasT, attn_ws);
        proj_mfma_kernel<<<1024, 256, 0, stream>>>(attn_ws, proj_w, proj_b, x, n1w, n1b, x1_ws);
        prep_weights<<<576, 256, 0, stream>>>(w1, w2, (unsigned int*)w1b, (unsigned int*)w2b);
        mlp_mfma_kernel<<<2048, 256, 0, stream>>>(x1_ws, w1b, b1, w2b, b2, n2w, n2b, out);
    }
}